// Round 1
// baseline (1634.601 us; speedup 1.0000x reference)
//
#include <hip/hip_runtime.h>

// ---------------------------------------------------------------------------
// STTConformerBlock: B=4 T=2048 D=512 H=8 DH=64 INNER=2048 K=31, all f32 I/O.
// Strategy: bf16 MFMA GEMMs (f32 accum) + f32 elementwise/reduction kernels.
// ---------------------------------------------------------------------------

typedef float  f32x4  __attribute__((ext_vector_type(4)));
typedef __bf16 bf16x8 __attribute__((ext_vector_type(8)));
typedef unsigned short u16x8 __attribute__((ext_vector_type(8)));

#define DEVI __device__ __forceinline__

static constexpr int CB = 4, CT = 2048, CD = 512, CH = 8, CDH = 64, CINNER = 2048, CK = 31;
static constexpr int CBT = CB * CT;          // 8192 rows
static constexpr long ROWSTRIDE_B = (long)CT * CD;  // per-batch stride in floats

DEVI unsigned short f2bf(float f) {
  unsigned u = __builtin_bit_cast(unsigned, f);
  u += 0x7FFFu + ((u >> 16) & 1u);          // round-to-nearest-even
  return (unsigned short)(u >> 16);
}
DEVI float sigm(float x) { return 1.0f / (1.0f + expf(-x)); }

enum { EPI_NONE = 0, EPI_SILU = 1, EPI_RES = 2 };

// ---------------------------------------------------------------------------
// Generic bf16-MFMA GEMM: C[M,N] = A[M,K] @ B[K,N] (+bias, epilogue)
// BTR=true: B passed row-major [N,K] (i.e. computes A @ B^T) -> used for QK^T.
// Batched via blockIdx.z: offsets (z/ZH)*s?1 + (z%ZH)*s?2.
// Tile: BM x BN, BK=32, 256 threads = 4 waves (2x2), wave tile (BM/2)x(BN/2),
// fragments 16x16x32. A/B staged to LDS as bf16 with +8 ushort padding.
// ---------------------------------------------------------------------------
template<int BM, int BN, int EPI, bool BTR>
__global__ __launch_bounds__(256) void gemm_k(
    const float* __restrict__ A, const float* __restrict__ Bm,
    const float* __restrict__ bias, const float* __restrict__ res,
    float* __restrict__ C,
    int lda, int ldb, int ldc, int Kd, float scale, int ZH,
    long sA1, long sA2, long sB1, long sB2, long sC1, long sC2)
{
  constexpr int LDP = 40;   // 32 bf16 + 8 pad -> 80B row stride (2-way bank alias only)
  __shared__ __align__(16) unsigned short As[BM][LDP];
  __shared__ __align__(16) unsigned short Bs[BN][LDP];

  const int z = blockIdx.z;
  A  += (long)(z / ZH) * sA1 + (long)(z % ZH) * sA2;
  Bm += (long)(z / ZH) * sB1 + (long)(z % ZH) * sB2;
  const long oC = (long)(z / ZH) * sC1 + (long)(z % ZH) * sC2;
  C += oC;
  if (EPI == EPI_RES) res += oC;

  const int m0 = blockIdx.y * BM, n0 = blockIdx.x * BN;
  const int tid = threadIdx.x;
  const int wid = tid >> 6, lane = tid & 63;
  const int lrow = lane & 15, lk = lane >> 4;
  constexpr int FM = BM / 32, FN = BN / 32;
  const int wm = (wid >> 1) * (BM / 2), wn = (wid & 1) * (BN / 2);

  f32x4 acc[FM][FN] = {};

  for (int k0 = 0; k0 < Kd; k0 += 32) {
    // ---- stage A tile: BM x 32 (units of 8 floats) ----
#pragma unroll
    for (int it = 0; it < (BM * 4) / 256; ++it) {
      int u = tid + it * 256;
      int r = u >> 2, ch = (u & 3) * 8;
      const float* s = A + (long)(m0 + r) * lda + (k0 + ch);
      float4 f0 = *(const float4*)s;
      float4 f1 = *(const float4*)(s + 4);
      u16x8 pk;
      pk[0] = f2bf(f0.x); pk[1] = f2bf(f0.y); pk[2] = f2bf(f0.z); pk[3] = f2bf(f0.w);
      pk[4] = f2bf(f1.x); pk[5] = f2bf(f1.y); pk[6] = f2bf(f1.z); pk[7] = f2bf(f1.w);
      *(u16x8*)&As[r][ch] = pk;
    }
    // ---- stage B tile into Bs[n][k] ----
    if (BTR) {
      // B is [N,K] row-major: direct copy of rows (this is how K^T loads as B)
#pragma unroll
      for (int it = 0; it < (BN * 4) / 256; ++it) {
        int u = tid + it * 256;
        int r = u >> 2, ch = (u & 3) * 8;
        const float* s = Bm + (long)(n0 + r) * ldb + (k0 + ch);
        float4 f0 = *(const float4*)s;
        float4 f1 = *(const float4*)(s + 4);
        u16x8 pk;
        pk[0] = f2bf(f0.x); pk[1] = f2bf(f0.y); pk[2] = f2bf(f0.z); pk[3] = f2bf(f0.w);
        pk[4] = f2bf(f1.x); pk[5] = f2bf(f1.y); pk[6] = f2bf(f1.z); pk[7] = f2bf(f1.w);
        *(u16x8*)&Bs[r][ch] = pk;
      }
    } else {
      // B is [K,N] row-major: coalesced read over n, transposed scalar LDS writes
      int kk = tid >> 3;
      int nseg = (tid & 7) * (BN / 8);
      const float* s = Bm + (long)(k0 + kk) * ldb + (n0 + nseg);
#pragma unroll
      for (int v = 0; v < BN / 32; ++v) {
        float4 f = *(const float4*)(s + v * 4);
        Bs[nseg + v * 4 + 0][kk] = f2bf(f.x);
        Bs[nseg + v * 4 + 1][kk] = f2bf(f.y);
        Bs[nseg + v * 4 + 2][kk] = f2bf(f.z);
        Bs[nseg + v * 4 + 3][kk] = f2bf(f.w);
      }
    }
    __syncthreads();

    bf16x8 av[FM], bv[FN];
#pragma unroll
    for (int i = 0; i < FM; ++i)
      av[i] = *(const bf16x8*)&As[wm + i * 16 + lrow][lk * 8];
#pragma unroll
    for (int j = 0; j < FN; ++j)
      bv[j] = *(const bf16x8*)&Bs[wn + j * 16 + lrow][lk * 8];
#pragma unroll
    for (int i = 0; i < FM; ++i)
#pragma unroll
      for (int j = 0; j < FN; ++j)
        acc[i][j] = __builtin_amdgcn_mfma_f32_16x16x32_bf16(av[i], bv[j], acc[i][j], 0, 0, 0);
    __syncthreads();
  }

  // ---- epilogue: D row=(lane>>4)*4+r, col=lane&15 ----
#pragma unroll
  for (int j = 0; j < FN; ++j) {
    int col = n0 + wn + j * 16 + lrow;
    float bb = bias ? bias[col] : 0.0f;
#pragma unroll
    for (int i = 0; i < FM; ++i) {
#pragma unroll
      for (int r = 0; r < 4; ++r) {
        int row = m0 + wm + i * 16 + lk * 4 + r;
        float v = acc[i][j][r] + bb;
        if (EPI == EPI_SILU) v *= sigm(v);
        long idx = (long)row * ldc + col;
        if (EPI == EPI_RES) v = res[idx] + scale * v;
        C[idx] = v;
      }
    }
  }
}

// ---------------------------------------------------------------------------
// LayerNorm over D=512, one block (256 thr) per row, float2 per thread.
// ---------------------------------------------------------------------------
__global__ __launch_bounds__(256) void ln_k(
    const float* __restrict__ in, const float* __restrict__ g,
    const float* __restrict__ b, float* __restrict__ out)
{
  __shared__ float rs[4], rq[4];
  const long row = blockIdx.x;
  const int tid = threadIdx.x;
  float2 v = ((const float2*)(in + row * CD))[tid];
  float s = v.x + v.y, q = v.x * v.x + v.y * v.y;
#pragma unroll
  for (int o = 32; o; o >>= 1) { s += __shfl_xor(s, o); q += __shfl_xor(q, o); }
  if ((tid & 63) == 0) { rs[tid >> 6] = s; rq[tid >> 6] = q; }
  __syncthreads();
  s = rs[0] + rs[1] + rs[2] + rs[3];
  q = rq[0] + rq[1] + rq[2] + rq[3];
  float mean = s * (1.0f / CD);
  float var  = q * (1.0f / CD) - mean * mean;
  float rstd = rsqrtf(var + 1e-5f);
  float2 gg = ((const float2*)g)[tid];
  float2 bb = ((const float2*)b)[tid];
  float2 o2;
  o2.x = (v.x - mean) * rstd * gg.x + bb.x;
  o2.y = (v.y - mean) * rstd * gg.y + bb.y;
  ((float2*)(out + row * CD))[tid] = o2;
}

// ---------------------------------------------------------------------------
// RoPE cos/sin table: [T][32] each.
// ---------------------------------------------------------------------------
__global__ void rope_table_k(float* __restrict__ cosT, float* __restrict__ sinT)
{
  int tid = blockIdx.x * 256 + threadIdx.x;     // T*32 = 65536
  int t = tid >> 5, i = tid & 31;
  float freq = expf(-(float)i * (9.210340371976184f / 32.0f)); // 10000^(-i/32)
  float ang = (float)t * freq;
  cosT[tid] = cosf(ang);
  sinT[tid] = sinf(ang);
}

// In-place RoPE on q and k; one thread per (pair in q)+(same pair in k).
__global__ __launch_bounds__(256) void rope_k(
    float* __restrict__ q, float* __restrict__ k,
    const float* __restrict__ cosT, const float* __restrict__ sinT)
{
  long p = (long)blockIdx.x * 256 + threadIdx.x;   // B*T*256 pairs = 2097152
  int i = (int)(p & 31);
  int t = (int)((p >> 8) & (CT - 1));
  float c = cosT[t * 32 + i], s = sinT[t * 32 + i];
  float2* q2 = (float2*)q;
  float2 v = q2[p];
  q2[p] = make_float2(v.x * c - v.y * s, v.x * s + v.y * c);
  float2* k2 = (float2*)k;
  v = k2[p];
  k2[p] = make_float2(v.x * c - v.y * s, v.x * s + v.y * c);
}

// ---------------------------------------------------------------------------
// Row softmax over 2048 with scale 1/8 folded in. One block per row.
// ---------------------------------------------------------------------------
__global__ __launch_bounds__(256) void softmax_k(float* __restrict__ sc)
{
  __shared__ float rr[4];
  float* p = sc + (long)blockIdx.x * 2048;
  const int tid = threadIdx.x;
  float4 a = ((float4*)p)[tid];
  float4 b = ((float4*)p)[tid + 256];
  float m = fmaxf(fmaxf(fmaxf(a.x, a.y), fmaxf(a.z, a.w)),
                  fmaxf(fmaxf(b.x, b.y), fmaxf(b.z, b.w)));
#pragma unroll
  for (int o = 32; o; o >>= 1) m = fmaxf(m, __shfl_xor(m, o));
  if ((tid & 63) == 0) rr[tid >> 6] = m;
  __syncthreads();
  m = fmaxf(fmaxf(rr[0], rr[1]), fmaxf(rr[2], rr[3]));
  __syncthreads();
  a.x = expf((a.x - m) * 0.125f); a.y = expf((a.y - m) * 0.125f);
  a.z = expf((a.z - m) * 0.125f); a.w = expf((a.w - m) * 0.125f);
  b.x = expf((b.x - m) * 0.125f); b.y = expf((b.y - m) * 0.125f);
  b.z = expf((b.z - m) * 0.125f); b.w = expf((b.w - m) * 0.125f);
  float s = a.x + a.y + a.z + a.w + b.x + b.y + b.z + b.w;
#pragma unroll
  for (int o = 32; o; o >>= 1) s += __shfl_xor(s, o);
  if ((tid & 63) == 0) rr[tid >> 6] = s;
  __syncthreads();
  s = rr[0] + rr[1] + rr[2] + rr[3];
  float inv = 1.0f / s;
  a.x *= inv; a.y *= inv; a.z *= inv; a.w *= inv;
  b.x *= inv; b.y *= inv; b.z *= inv; b.w *= inv;
  ((float4*)p)[tid] = a;
  ((float4*)p)[tid + 256] = b;
}

// GLU: out[r,c] = t[r,c] * sigmoid(t[r, 512+c]);  t rows are 1024 wide.
__global__ __launch_bounds__(256) void glu_k(
    const float* __restrict__ t, float* __restrict__ out)
{
  long idx = (long)blockIdx.x * 256 + threadIdx.x;  // BT*D
  long row = idx >> 9;
  int  c = (int)(idx & 511);
  const float* r = t + row * 1024;
  out[idx] = r[c] * sigm(r[c + 512]);
}

// Depthwise conv1d over T, K=31, pad 15, layout (B,T,D), channel-fastest.
__global__ __launch_bounds__(256) void dwconv_k(
    const float* __restrict__ in, const float* __restrict__ w,
    const float* __restrict__ wb, float* __restrict__ out)
{
  long idx = (long)blockIdx.x * 256 + threadIdx.x;  // B*T*D
  int c = (int)(idx & 511);
  int t = (int)((idx >> 9) & (CT - 1));
  int b = (int)(idx >> 20);
  const float* base = in + (long)b * CT * CD;
  float acc = wb[c];
#pragma unroll
  for (int j = 0; j < CK; ++j) {
    int tt = t + j - CK / 2;
    if (tt >= 0 && tt < CT)
      acc += base[(long)tt * CD + c] * w[c * CK + j];
  }
  out[idx] = acc;
}

// BatchNorm stats over (B,T) per channel: partial sums (64 blocks),
// then finalize (mean, rsqrt(var+eps)).
__global__ __launch_bounds__(256) void bn_part_k(
    const float* __restrict__ in, float* __restrict__ psum, float* __restrict__ psq)
{
  const int blk = blockIdx.x;        // 64
  const int tid = threadIdx.x;       // 256
  const int c0 = tid, c1 = tid + 256;
  const int rows = CBT / 64;         // 128
  const float* base = in + (long)blk * rows * CD;
  float s0 = 0, q0 = 0, s1 = 0, q1 = 0;
  for (int r = 0; r < rows; ++r) {
    float v0 = base[(long)r * CD + c0]; s0 += v0; q0 += v0 * v0;
    float v1 = base[(long)r * CD + c1]; s1 += v1; q1 += v1 * v1;
  }
  psum[blk * CD + c0] = s0; psq[blk * CD + c0] = q0;
  psum[blk * CD + c1] = s1; psq[blk * CD + c1] = q1;
}

__global__ __launch_bounds__(256) void bn_fin_k(
    const float* __restrict__ psum, const float* __restrict__ psq,
    float* __restrict__ stat)
{
  int c = blockIdx.x * 256 + threadIdx.x;   // 512
  float s = 0, q = 0;
  for (int i = 0; i < 64; ++i) { s += psum[i * CD + c]; q += psq[i * CD + c]; }
  float mean = s * (1.0f / CBT);
  float var  = q * (1.0f / CBT) - mean * mean;
  stat[c] = mean;
  stat[CD + c] = rsqrtf(var + 1e-5f);
}

// Apply BN (affine) + SiLU, in place.
__global__ __launch_bounds__(256) void bn_app_k(
    float* __restrict__ h, const float* __restrict__ stat,
    const float* __restrict__ g, const float* __restrict__ b)
{
  long idx = (long)blockIdx.x * 256 + threadIdx.x;
  int c = (int)(idx & 511);
  float v = (h[idx] - stat[c]) * stat[CD + c] * g[c] + b[c];
  h[idx] = v * sigm(v);
}

// ---------------------------------------------------------------------------
// Host launcher
// ---------------------------------------------------------------------------
extern "C" void kernel_launch(void* const* d_in, const int* in_sizes, int n_in,
                              void* d_out, int out_size, void* d_ws, size_t ws_size,
                              hipStream_t stream)
{
  const float* x        = (const float*)d_in[0];
  const float* ff1_lng  = (const float*)d_in[1];
  const float* ff1_lnb  = (const float*)d_in[2];
  const float* ff1_w1   = (const float*)d_in[3];
  const float* ff1_b1   = (const float*)d_in[4];
  const float* ff1_w2   = (const float*)d_in[5];
  const float* ff1_b2   = (const float*)d_in[6];
  const float* attn_lng = (const float*)d_in[7];
  const float* attn_lnb = (const float*)d_in[8];
  const float* wq       = (const float*)d_in[9];
  const float* wk       = (const float*)d_in[10];
  const float* wv       = (const float*)d_in[11];
  const float* wo       = (const float*)d_in[12];
  const float* conv_lng = (const float*)d_in[13];
  const float* conv_lnb = (const float*)d_in[14];
  const float* pw1_w    = (const float*)d_in[15];
  const float* pw1_b    = (const float*)d_in[16];
  const float* dw_w     = (const float*)d_in[17];
  const float* dw_b     = (const float*)d_in[18];
  const float* bn_g     = (const float*)d_in[19];
  const float* bn_b     = (const float*)d_in[20];
  const float* pw2_w    = (const float*)d_in[21];
  const float* pw2_b    = (const float*)d_in[22];
  const float* ff2_lng  = (const float*)d_in[23];
  const float* ff2_lnb  = (const float*)d_in[24];
  const float* ff2_w1   = (const float*)d_in[25];
  const float* ff2_b1   = (const float*)d_in[26];
  const float* ff2_w2   = (const float*)d_in[27];
  const float* ff2_b2   = (const float*)d_in[28];
  const float* out_lng  = (const float*)d_in[29];
  const float* out_lnb  = (const float*)d_in[30];
  float* out = (float*)d_out;

  // workspace carve-up (floats); total ~161 MiB
  float* w = (float*)d_ws;
  float* bufX = w; w += (long)CBT * CD;       // residual stream
  float* bufH = w; w += (long)CBT * CD;       // LN out / GLU out
  float* bufQ = w; w += (long)CBT * CD;
  float* bufK = w; w += (long)CBT * CD;
  float* bufV = w; w += (long)CBT * CD;
  float* bufO = w; w += (long)CBT * CD;       // attn out / conv buffer
  float* bufT = w; w += (long)CBT * CINNER;   // FF hidden / pw1 out / score chunks
  float* cosT = w; w += CT * 32;
  float* sinT = w; w += CT * 32;
  float* psum = w; w += 64 * CD;
  float* psq  = w; w += 64 * CD;
  float* stat = w; w += 2 * CD;

  const dim3 blk(256);
  const long TD = ROWSTRIDE_B;         // 1048576 (per-batch stride, floats)
  const long SCH = 256L * 2048;        // score-chunk per-(b,h) stride = 524288

  // RoPE tables
  rope_table_k<<<dim3(CT * 32 / 256), blk, 0, stream>>>(cosT, sinT);

  // ---- FF1: x += 0.5*FF(LN(x)) ----
  ln_k<<<dim3(CBT), blk, 0, stream>>>(x, ff1_lng, ff1_lnb, bufH);
  gemm_k<128,128,EPI_SILU,false><<<dim3(16,64,1), blk, 0, stream>>>(
      bufH, ff1_w1, ff1_b1, nullptr, bufT, CD, CINNER, CINNER, CD, 0.f, 1,0,0,0,0,0,0);
  gemm_k<128,128,EPI_RES,false><<<dim3(4,64,1), blk, 0, stream>>>(
      bufT, ff1_w2, ff1_b2, x, bufX, CINNER, CD, CD, CINNER, 0.5f, 1,0,0,0,0,0,0);

  // ---- Attention ----
  ln_k<<<dim3(CBT), blk, 0, stream>>>(bufX, attn_lng, attn_lnb, bufH);
  gemm_k<128,128,EPI_NONE,false><<<dim3(4,64,1), blk, 0, stream>>>(
      bufH, wq, nullptr, nullptr, bufQ, CD, CD, CD, CD, 0.f, 1,0,0,0,0,0,0);
  gemm_k<128,128,EPI_NONE,false><<<dim3(4,64,1), blk, 0, stream>>>(
      bufH, wk, nullptr, nullptr, bufK, CD, CD, CD, CD, 0.f, 1,0,0,0,0,0,0);
  gemm_k<128,128,EPI_NONE,false><<<dim3(4,64,1), blk, 0, stream>>>(
      bufH, wv, nullptr, nullptr, bufV, CD, CD, CD, CD, 0.f, 1,0,0,0,0,0,0);
  rope_k<<<dim3(CB * CT * 256 / 256), blk, 0, stream>>>(bufQ, bufK, cosT, sinT);

  for (int c = 0; c < 8; ++c) {
    const float* Qc = bufQ + (long)c * 256 * CD;
    float*       Oc = bufO + (long)c * 256 * CD;
    // S = Qc @ K^T  (batched over z = b*8+h)
    gemm_k<128,128,EPI_NONE,true><<<dim3(16,2,32), blk, 0, stream>>>(
        Qc, bufK, nullptr, nullptr, bufT, CD, CD, 2048, CDH, 0.f,
        CH, TD, CDH, TD, CDH, 8*SCH, SCH);
    softmax_k<<<dim3(32 * 256), blk, 0, stream>>>(bufT);
    // O = P @ V
    gemm_k<64,64,EPI_NONE,false><<<dim3(1,4,32), blk, 0, stream>>>(
        bufT, bufV, nullptr, nullptr, Oc, 2048, CD, CD, 2048, 0.f,
        CH, 8*SCH, SCH, TD, CDH, TD, CDH);
  }
  gemm_k<128,128,EPI_RES,false><<<dim3(4,64,1), blk, 0, stream>>>(
      bufO, wo, nullptr, bufX, bufX, CD, CD, CD, CD, 1.0f, 1,0,0,0,0,0,0);

  // ---- Conv module ----
  ln_k<<<dim3(CBT), blk, 0, stream>>>(bufX, conv_lng, conv_lnb, bufH);
  gemm_k<128,128,EPI_NONE,false><<<dim3(8,64,1), blk, 0, stream>>>(
      bufH, pw1_w, pw1_b, nullptr, bufT, CD, 2*CD, 2*CD, CD, 0.f, 1,0,0,0,0,0,0);
  glu_k<<<dim3(CBT * CD / 256), blk, 0, stream>>>(bufT, bufH);
  dwconv_k<<<dim3(CBT * CD / 256), blk, 0, stream>>>(bufH, dw_w, dw_b, bufO);
  bn_part_k<<<dim3(64), blk, 0, stream>>>(bufO, psum, psq);
  bn_fin_k<<<dim3(2), blk, 0, stream>>>(psum, psq, stat);
  bn_app_k<<<dim3(CBT * CD / 256), blk, 0, stream>>>(bufO, stat, bn_g, bn_b);
  gemm_k<128,128,EPI_RES,false><<<dim3(4,64,1), blk, 0, stream>>>(
      bufO, pw2_w, pw2_b, bufX, bufX, CD, CD, CD, CD, 1.0f, 1,0,0,0,0,0,0);

  // ---- FF2 ----
  ln_k<<<dim3(CBT), blk, 0, stream>>>(bufX, ff2_lng, ff2_lnb, bufH);
  gemm_k<128,128,EPI_SILU,false><<<dim3(16,64,1), blk, 0, stream>>>(
      bufH, ff2_w1, ff2_b1, nullptr, bufT, CD, CINNER, CINNER, CD, 0.f, 1,0,0,0,0,0,0);
  gemm_k<128,128,EPI_RES,false><<<dim3(4,64,1), blk, 0, stream>>>(
      bufT, ff2_w2, ff2_b2, bufX, bufX, CINNER, CD, CD, CINNER, 0.5f, 1,0,0,0,0,0,0);

  // ---- Output LN ----
  ln_k<<<dim3(CBT), blk, 0, stream>>>(bufX, out_lng, out_lnb, out);

  (void)in_sizes; (void)n_in; (void)out_size; (void)ws_size;
}

// Round 2
// 718.673 us; speedup vs baseline: 2.2745x; 2.2745x over previous
//
#include <hip/hip_runtime.h>

// ---------------------------------------------------------------------------
// STTConformerBlock: B=4 T=2048 D=512 H=8 DH=64 INNER=2048 K=31, f32 I/O.
// All GEMMs: bf16 MFMA (16x16x32), B pre-transposed to [N][K] bf16,
// global_load_lds width-16 staging, BK=64, f32 accumulate.
// ---------------------------------------------------------------------------

typedef float  f32x4  __attribute__((ext_vector_type(4)));
typedef __bf16 bf16_t;
typedef __bf16 bf16x8 __attribute__((ext_vector_type(8)));
typedef unsigned short u16;
typedef unsigned short u16x4 __attribute__((ext_vector_type(4)));
typedef unsigned short u16x8 __attribute__((ext_vector_type(8)));

#define DEVI __device__ __forceinline__

static constexpr int CB = 4, CT = 2048, CD = 512, CH = 8, CDH = 64, CINNER = 2048, CK = 31;
static constexpr int CBT = CB * CT;                    // 8192 rows
static constexpr long TDE = (long)CT * CD;             // per-batch elements

DEVI u16 f2bf(float f) {
  unsigned u = __builtin_bit_cast(unsigned, f);
  u += 0x7FFFu + ((u >> 16) & 1u);
  return (u16)(u >> 16);
}
DEVI float bf2f(u16 h) { return __builtin_bit_cast(float, (unsigned)h << 16); }
DEVI float sigm(float x) { return 1.0f / (1.0f + expf(-x)); }

DEVI void gload16(const bf16_t* g, bf16_t* l) {
  __builtin_amdgcn_global_load_lds(
      (const __attribute__((address_space(1))) unsigned int*)g,
      (__attribute__((address_space(3))) unsigned int*)l, 16, 0, 0);
}

enum { EPI_BF = 0, EPI_SILU_BF = 1, EPI_RES = 2 };

// ---------------------------------------------------------------------------
// bf16 GEMM: C[M,N] = epi( A[M,K] @ B[N,K]^T * scale + bias )
// z-batched: per-operand linear offset z*s{A,B,C}.
// BM x BN tile, BK=64, 256 thr = 4 waves (2x2), frags 16x16x32.
// ---------------------------------------------------------------------------
template<int BM, int BN, int EPI>
__global__ __launch_bounds__(256) void gemm_bf(
    const bf16_t* __restrict__ A, const bf16_t* __restrict__ B,
    const float* __restrict__ bias, const float* __restrict__ res,
    void* __restrict__ Cv,
    int lda, int ldb, int ldc, int Kd, float scale,
    long sA, long sB, long sC)
{
  __shared__ __align__(16) bf16_t As[BM * 64];
  __shared__ __align__(16) bf16_t Bs[BN * 64];

  const long z = blockIdx.z;
  A += z * sA;
  B += z * sB;
  const long oC = z * sC;

  const int m0 = blockIdx.y * BM, n0 = blockIdx.x * BN;
  const int tid = threadIdx.x;
  const int wid = tid >> 6, lane = tid & 63;
  const int lrow = lane & 15, lk = lane >> 4;
  constexpr int FM = BM / 32, FN = BN / 32;
  const int wm = (wid >> 1) * (BM / 2), wn = (wid & 1) * (BN / 2);
  const int r8 = tid >> 3, c8 = (tid & 7) * 8;

  f32x4 acc[FM][FN] = {};

  for (int k0 = 0; k0 < Kd; k0 += 64) {
    const bf16_t* ga = A + (long)(m0 + r8) * lda + (k0 + c8);
    const bf16_t* gb = B + (long)(n0 + r8) * ldb + (k0 + c8);
#pragma unroll
    for (int it = 0; it < BM / 32; ++it)
      gload16(ga + (long)it * 32 * lda, &As[tid * 8 + it * 2048]);
#pragma unroll
    for (int it = 0; it < BN / 32; ++it)
      gload16(gb + (long)it * 32 * ldb, &Bs[tid * 8 + it * 2048]);
    __syncthreads();

    bf16x8 av[2][FM], bv[2][FN];
#pragma unroll
    for (int kk = 0; kk < 2; ++kk) {
#pragma unroll
      for (int i = 0; i < FM; ++i)
        av[kk][i] = *(const bf16x8*)&As[(wm + i * 16 + lrow) * 64 + kk * 32 + lk * 8];
#pragma unroll
      for (int j = 0; j < FN; ++j)
        bv[kk][j] = *(const bf16x8*)&Bs[(wn + j * 16 + lrow) * 64 + kk * 32 + lk * 8];
    }
#pragma unroll
    for (int kk = 0; kk < 2; ++kk)
#pragma unroll
      for (int i = 0; i < FM; ++i)
#pragma unroll
        for (int j = 0; j < FN; ++j)
          acc[i][j] = __builtin_amdgcn_mfma_f32_16x16x32_bf16(av[kk][i], bv[kk][j], acc[i][j], 0, 0, 0);
    __syncthreads();
  }

  // epilogue: C row=(lane>>4)*4+r, col=lane&15
#pragma unroll
  for (int j = 0; j < FN; ++j) {
    int col = n0 + wn + j * 16 + lrow;
    float bb = bias ? bias[col] : 0.0f;
#pragma unroll
    for (int i = 0; i < FM; ++i) {
#pragma unroll
      for (int r = 0; r < 4; ++r) {
        int row = m0 + wm + i * 16 + lk * 4 + r;
        long idx = oC + (long)row * ldc + col;
        float v = (acc[i][j][r] + bb) * scale;
        if constexpr (EPI == EPI_SILU_BF) v *= sigm(v);
        if constexpr (EPI == EPI_RES) {
          ((float*)Cv)[idx] = res[idx] + v;
        } else {
          ((bf16_t*)Cv)[idx] = (bf16_t)v;
        }
      }
    }
  }
}

// ---------------------------------------------------------------------------
// Weight convert+transpose: w[K][N] f32 -> o[N][K] bf16. 64x64 tiles.
// ---------------------------------------------------------------------------
__global__ __launch_bounds__(256) void wtrans_k(
    const float* __restrict__ w, u16* __restrict__ o, int Kd, int N)
{
  __shared__ u16 lt[64][72];
  const int k0 = blockIdx.y * 64, n0 = blockIdx.x * 64;
  const int tid = threadIdx.x;
#pragma unroll
  for (int it = 0; it < 4; ++it) {
    int kk = (tid >> 4) + it * 16, nn = (tid & 15) * 4;
    float4 f = *(const float4*)(w + (long)(k0 + kk) * N + n0 + nn);
    lt[kk][nn + 0] = f2bf(f.x); lt[kk][nn + 1] = f2bf(f.y);
    lt[kk][nn + 2] = f2bf(f.z); lt[kk][nn + 3] = f2bf(f.w);
  }
  __syncthreads();
#pragma unroll
  for (int it = 0; it < 2; ++it) {
    int nn = (tid >> 3) + it * 32, kk = (tid & 7) * 8;
    u16x8 pk;
#pragma unroll
    for (int e = 0; e < 8; ++e) pk[e] = lt[kk + e][nn];
    *(u16x8*)(o + (long)(n0 + nn) * Kd + k0 + kk) = pk;
  }
}

// V[b][t][h*64+d] bf16 -> VT[bh][d][t] bf16, 64x64 tiles per (bh, t-tile).
__global__ __launch_bounds__(256) void vtrans_k(
    const u16* __restrict__ v, u16* __restrict__ vt)
{
  __shared__ u16 lt[64][72];
  const int bh = blockIdx.y, b = bh >> 3, h = bh & 7;
  const int t0 = blockIdx.x * 64;
  const int tid = threadIdx.x;
#pragma unroll
  for (int it = 0; it < 2; ++it) {
    int tt = (tid >> 3) + it * 32, dd = (tid & 7) * 8;
    u16x8 vv = *(const u16x8*)(v + ((long)b * CT + t0 + tt) * CD + h * 64 + dd);
#pragma unroll
    for (int e = 0; e < 8; ++e) lt[tt][dd + e] = vv[e];
  }
  __syncthreads();
#pragma unroll
  for (int it = 0; it < 2; ++it) {
    int dd = (tid >> 3) + it * 32, tt = (tid & 7) * 8;
    u16x8 pk;
#pragma unroll
    for (int e = 0; e < 8; ++e) pk[e] = lt[tt + e][dd];
    *(u16x8*)(vt + ((long)bh * 64 + dd) * CT + t0 + tt) = pk;
  }
}

// dw_w[512][31] f32 -> wT[31][512] f32
__global__ void dwt_k(const float* __restrict__ w, float* __restrict__ o)
{
  int i = blockIdx.x * 256 + threadIdx.x;
  if (i < 512 * 31) { int c = i / 31, k = i % 31; o[k * 512 + c] = w[i]; }
}

// ---------------------------------------------------------------------------
// LayerNorm over D=512, one block per row; OT = float or bf16 out.
// ---------------------------------------------------------------------------
template<int OBF>
__global__ __launch_bounds__(256) void ln_k(
    const float* __restrict__ in, const float* __restrict__ g,
    const float* __restrict__ b, void* __restrict__ out)
{
  __shared__ float rs[4], rq[4];
  const long row = blockIdx.x;
  const int tid = threadIdx.x;
  float2 v = ((const float2*)(in + row * CD))[tid];
  float s = v.x + v.y, q = v.x * v.x + v.y * v.y;
#pragma unroll
  for (int o = 32; o; o >>= 1) { s += __shfl_xor(s, o); q += __shfl_xor(q, o); }
  if ((tid & 63) == 0) { rs[tid >> 6] = s; rq[tid >> 6] = q; }
  __syncthreads();
  s = rs[0] + rs[1] + rs[2] + rs[3];
  q = rq[0] + rq[1] + rq[2] + rq[3];
  float mean = s * (1.0f / CD);
  float var = q * (1.0f / CD) - mean * mean;
  float rstd = rsqrtf(var + 1e-5f);
  float2 gg = ((const float2*)g)[tid];
  float2 bb = ((const float2*)b)[tid];
  float ox = (v.x - mean) * rstd * gg.x + bb.x;
  float oy = (v.y - mean) * rstd * gg.y + bb.y;
  if (OBF) {
    unsigned pk = ((unsigned)f2bf(oy) << 16) | f2bf(ox);
    ((unsigned*)out)[row * 256 + tid] = pk;
  } else {
    ((float2*)out)[row * 256 + tid] = make_float2(ox, oy);
  }
}

// RoPE cos/sin table
__global__ void rope_table_k(float* __restrict__ cosT, float* __restrict__ sinT)
{
  int tid = blockIdx.x * 256 + threadIdx.x;     // T*32
  int t = tid >> 5, i = tid & 31;
  float freq = expf(-(float)i * (9.210340371976184f / 32.0f));
  float ang = (float)t * freq;
  cosT[tid] = cosf(ang);
  sinT[tid] = sinf(ang);
}

// In-place RoPE on bf16 q and k (pairs packed in one u32).
__global__ __launch_bounds__(256) void rope_k(
    unsigned* __restrict__ q, unsigned* __restrict__ k,
    const float* __restrict__ cosT, const float* __restrict__ sinT)
{
  long p = (long)blockIdx.x * 256 + threadIdx.x;   // B*T*256 pairs
  int i = (int)(p & 31);
  int t = (int)((p >> 8) & (CT - 1));
  float c = cosT[t * 32 + i], s = sinT[t * 32 + i];
  unsigned v = q[p];
  float xe = bf2f((u16)v), xo = bf2f((u16)(v >> 16));
  q[p] = ((unsigned)f2bf(xe * s + xo * c) << 16) | f2bf(xe * c - xo * s);
  v = k[p];
  xe = bf2f((u16)v); xo = bf2f((u16)(v >> 16));
  k[p] = ((unsigned)f2bf(xe * s + xo * c) << 16) | f2bf(xe * c - xo * s);
}

// Row softmax over 2048 bf16 (scale already folded into scores).
__global__ __launch_bounds__(256) void softmax_k(u16* __restrict__ sc)
{
  __shared__ float rr[4];
  u16* p = sc + (long)blockIdx.x * 2048;
  const int tid = threadIdx.x;
  u16x8 v = ((const u16x8*)p)[tid];
  float f[8];
#pragma unroll
  for (int e = 0; e < 8; ++e) f[e] = bf2f(v[e]);
  float m = f[0];
#pragma unroll
  for (int e = 1; e < 8; ++e) m = fmaxf(m, f[e]);
#pragma unroll
  for (int o = 32; o; o >>= 1) m = fmaxf(m, __shfl_xor(m, o));
  if ((tid & 63) == 0) rr[tid >> 6] = m;
  __syncthreads();
  m = fmaxf(fmaxf(rr[0], rr[1]), fmaxf(rr[2], rr[3]));
  __syncthreads();
  float s = 0;
#pragma unroll
  for (int e = 0; e < 8; ++e) { f[e] = expf(f[e] - m); s += f[e]; }
#pragma unroll
  for (int o = 32; o; o >>= 1) s += __shfl_xor(s, o);
  if ((tid & 63) == 0) rr[tid >> 6] = s;
  __syncthreads();
  s = rr[0] + rr[1] + rr[2] + rr[3];
  float inv = 1.0f / s;
#pragma unroll
  for (int e = 0; e < 8; ++e) v[e] = f2bf(f[e] * inv);
  ((u16x8*)p)[tid] = v;
}

// GLU: out[r][c] = t[r][c] * sigmoid(t[r][512+c]); t rows 1024 bf16, out bf16.
__global__ __launch_bounds__(256) void glu_k(
    const u16* __restrict__ t, u16* __restrict__ out)
{
  long idx = (long)blockIdx.x * 256 + threadIdx.x;  // BT*128
  long row = idx >> 7;
  int c4 = (int)(idx & 127) * 4;
  u16x4 a = *(const u16x4*)(t + row * 1024 + c4);
  u16x4 b = *(const u16x4*)(t + row * 1024 + 512 + c4);
  u16x4 o;
#pragma unroll
  for (int e = 0; e < 4; ++e) o[e] = f2bf(bf2f(a[e]) * sigm(bf2f(b[e])));
  *(u16x4*)(out + row * CD + c4) = o;
}

// Depthwise conv1d: bf16 in (GLU out), f32 out. 8 t-outputs x 4 channels/thread.
__global__ __launch_bounds__(256) void dwconv_k(
    const u16* __restrict__ in, const float* __restrict__ wT,
    const float* __restrict__ wb, float* __restrict__ out)
{
  long idx = (long)blockIdx.x * 256 + threadIdx.x;  // B*(T/8)*(D/4) = 131072
  int c4 = (int)(idx & 127) * 4;
  int t0 = (int)((idx >> 7) & 255) * 8;
  int b = (int)(idx >> 15);
  const u16* base = in + (long)b * CT * CD;
  float4 bias = *(const float4*)(wb + c4);
  float4 acc[8];
#pragma unroll
  for (int t = 0; t < 8; ++t) acc[t] = bias;
#pragma unroll
  for (int j = 0; j < 38; ++j) {
    int tr = t0 + j - 15;
    float4 row = make_float4(0.f, 0.f, 0.f, 0.f);
    if (tr >= 0 && tr < CT) {
      u16x4 rv = *(const u16x4*)(base + (long)tr * CD + c4);
      row = make_float4(bf2f(rv[0]), bf2f(rv[1]), bf2f(rv[2]), bf2f(rv[3]));
    }
#pragma unroll
    for (int t = 0; t < 8; ++t) {
      int k = j - t;
      if (k >= 0 && k < CK) {
        float4 w4 = *(const float4*)(wT + k * CD + c4);
        acc[t].x += row.x * w4.x; acc[t].y += row.y * w4.y;
        acc[t].z += row.z * w4.z; acc[t].w += row.w * w4.w;
      }
    }
  }
#pragma unroll
  for (int t = 0; t < 8; ++t)
    *(float4*)(out + ((long)b * CT + t0 + t) * CD + c4) = acc[t];
}

// BatchNorm stats over (B,T) per channel.
__global__ __launch_bounds__(256) void bn_part_k(
    const float* __restrict__ in, float* __restrict__ psum, float* __restrict__ psq)
{
  const int blk = blockIdx.x;        // 64
  const int tid = threadIdx.x;
  const int c0 = tid, c1 = tid + 256;
  const int rows = CBT / 64;
  const float* base = in + (long)blk * rows * CD;
  float s0 = 0, q0 = 0, s1 = 0, q1 = 0;
  for (int r = 0; r < rows; ++r) {
    float v0 = base[(long)r * CD + c0]; s0 += v0; q0 += v0 * v0;
    float v1 = base[(long)r * CD + c1]; s1 += v1; q1 += v1 * v1;
  }
  psum[blk * CD + c0] = s0; psq[blk * CD + c0] = q0;
  psum[blk * CD + c1] = s1; psq[blk * CD + c1] = q1;
}

__global__ __launch_bounds__(256) void bn_fin_k(
    const float* __restrict__ psum, const float* __restrict__ psq,
    float* __restrict__ stat)
{
  int c = blockIdx.x * 256 + threadIdx.x;
  float s = 0, q = 0;
  for (int i = 0; i < 64; ++i) { s += psum[i * CD + c]; q += psq[i * CD + c]; }
  float mean = s * (1.0f / CBT);
  float var = q * (1.0f / CBT) - mean * mean;
  stat[c] = mean;
  stat[CD + c] = rsqrtf(var + 1e-5f);
}

// BN affine + SiLU, f32 in -> bf16 out.
__global__ __launch_bounds__(256) void bn_app_k(
    const float* __restrict__ h, const float* __restrict__ stat,
    const float* __restrict__ g, const float* __restrict__ b,
    u16* __restrict__ out)
{
  long idx = (long)blockIdx.x * 256 + threadIdx.x;
  int c = (int)(idx & 511);
  float v = (h[idx] - stat[c]) * stat[CD + c] * g[c] + b[c];
  v = v * sigm(v);
  out[idx] = f2bf(v);
}

// ---------------------------------------------------------------------------
// Host launcher
// ---------------------------------------------------------------------------
extern "C" void kernel_launch(void* const* d_in, const int* in_sizes, int n_in,
                              void* d_out, int out_size, void* d_ws, size_t ws_size,
                              hipStream_t stream)
{
  const float* x        = (const float*)d_in[0];
  const float* ff1_lng  = (const float*)d_in[1];
  const float* ff1_lnb  = (const float*)d_in[2];
  const float* ff1_w1   = (const float*)d_in[3];
  const float* ff1_b1   = (const float*)d_in[4];
  const float* ff1_w2   = (const float*)d_in[5];
  const float* ff1_b2   = (const float*)d_in[6];
  const float* attn_lng = (const float*)d_in[7];
  const float* attn_lnb = (const float*)d_in[8];
  const float* wq       = (const float*)d_in[9];
  const float* wk       = (const float*)d_in[10];
  const float* wv       = (const float*)d_in[11];
  const float* wo       = (const float*)d_in[12];
  const float* conv_lng = (const float*)d_in[13];
  const float* conv_lnb = (const float*)d_in[14];
  const float* pw1_w    = (const float*)d_in[15];
  const float* pw1_b    = (const float*)d_in[16];
  const float* dw_w     = (const float*)d_in[17];
  const float* dw_b     = (const float*)d_in[18];
  const float* bn_g     = (const float*)d_in[19];
  const float* bn_b     = (const float*)d_in[20];
  const float* pw2_w    = (const float*)d_in[21];
  const float* pw2_b    = (const float*)d_in[22];
  const float* ff2_lng  = (const float*)d_in[23];
  const float* ff2_lnb  = (const float*)d_in[24];
  const float* ff2_w1   = (const float*)d_in[25];
  const float* ff2_b1   = (const float*)d_in[26];
  const float* ff2_w2   = (const float*)d_in[27];
  const float* ff2_b2   = (const float*)d_in[28];
  const float* out_lng  = (const float*)d_in[29];
  const float* out_lnb  = (const float*)d_in[30];
  float* out = (float*)d_out;

  // ---- workspace carve (256B-aligned) ----
  char* p = (char*)d_ws;
  auto alloc = [&](size_t bytes) { char* r = p; p += (bytes + 255) & ~(size_t)255; return r; };
  float*  bufX  = (float*)alloc((size_t)CBT * CD * 4);       // residual f32
  float*  bufC  = (float*)alloc((size_t)CBT * CD * 4);       // conv f32
  bf16_t* bufH  = (bf16_t*)alloc((size_t)CBT * CD * 2);      // LN/GLU/BN out bf16
  bf16_t* bufQ  = (bf16_t*)alloc((size_t)CBT * CD * 2);
  bf16_t* bufK  = (bf16_t*)alloc((size_t)CBT * CD * 2);
  bf16_t* bufV  = (bf16_t*)alloc((size_t)CBT * CD * 2);
  bf16_t* bufO  = (bf16_t*)alloc((size_t)CBT * CD * 2);
  bf16_t* bufVT = (bf16_t*)alloc((size_t)CBT * CD * 2);      // [bh][d][t]
  bf16_t* bufP  = (bf16_t*)alloc((size_t)8 * CT * CT * 2);   // scores / FF hidden
  bf16_t* w_ff1a = (bf16_t*)alloc((size_t)CD * CINNER * 2);
  bf16_t* w_ff1b = (bf16_t*)alloc((size_t)CD * CINNER * 2);
  bf16_t* w_q    = (bf16_t*)alloc((size_t)CD * CD * 2);
  bf16_t* w_k    = (bf16_t*)alloc((size_t)CD * CD * 2);
  bf16_t* w_v    = (bf16_t*)alloc((size_t)CD * CD * 2);
  bf16_t* w_o    = (bf16_t*)alloc((size_t)CD * CD * 2);
  bf16_t* w_pw1  = (bf16_t*)alloc((size_t)CD * 2 * CD * 2);
  bf16_t* w_pw2  = (bf16_t*)alloc((size_t)CD * CD * 2);
  bf16_t* w_ff2a = (bf16_t*)alloc((size_t)CD * CINNER * 2);
  bf16_t* w_ff2b = (bf16_t*)alloc((size_t)CD * CINNER * 2);
  float* dwT  = (float*)alloc((size_t)CK * CD * 4);
  float* cosT = (float*)alloc((size_t)CT * 32 * 4);
  float* sinT = (float*)alloc((size_t)CT * 32 * 4);
  float* psum = (float*)alloc((size_t)64 * CD * 4);
  float* psq  = (float*)alloc((size_t)64 * CD * 4);
  float* stat = (float*)alloc((size_t)2 * CD * 4);

  const dim3 blk(256);

  // ---- one-time prep: weight transposes, V^T later, RoPE table ----
  wtrans_k<<<dim3(CINNER / 64, CD / 64), blk, 0, stream>>>(ff1_w1, (u16*)w_ff1a, CD, CINNER);
  wtrans_k<<<dim3(CD / 64, CINNER / 64), blk, 0, stream>>>(ff1_w2, (u16*)w_ff1b, CINNER, CD);
  wtrans_k<<<dim3(CD / 64, CD / 64), blk, 0, stream>>>(wq, (u16*)w_q, CD, CD);
  wtrans_k<<<dim3(CD / 64, CD / 64), blk, 0, stream>>>(wk, (u16*)w_k, CD, CD);
  wtrans_k<<<dim3(CD / 64, CD / 64), blk, 0, stream>>>(wv, (u16*)w_v, CD, CD);
  wtrans_k<<<dim3(CD / 64, CD / 64), blk, 0, stream>>>(wo, (u16*)w_o, CD, CD);
  wtrans_k<<<dim3(2 * CD / 64, CD / 64), blk, 0, stream>>>(pw1_w, (u16*)w_pw1, CD, 2 * CD);
  wtrans_k<<<dim3(CD / 64, CD / 64), blk, 0, stream>>>(pw2_w, (u16*)w_pw2, CD, CD);
  wtrans_k<<<dim3(CINNER / 64, CD / 64), blk, 0, stream>>>(ff2_w1, (u16*)w_ff2a, CD, CINNER);
  wtrans_k<<<dim3(CD / 64, CINNER / 64), blk, 0, stream>>>(ff2_w2, (u16*)w_ff2b, CINNER, CD);
  dwt_k<<<dim3(62), blk, 0, stream>>>(dw_w, dwT);
  rope_table_k<<<dim3(CT * 32 / 256), blk, 0, stream>>>(cosT, sinT);

  // ---- FF1: x += 0.5*FF(LN(x)) ----
  ln_k<1><<<dim3(CBT), blk, 0, stream>>>(x, ff1_lng, ff1_lnb, bufH);
  gemm_bf<128, 128, EPI_SILU_BF><<<dim3(16, 64, 1), blk, 0, stream>>>(
      bufH, w_ff1a, ff1_b1, nullptr, bufP, CD, CD, CINNER, CD, 1.0f, 0, 0, 0);
  gemm_bf<128, 128, EPI_RES><<<dim3(4, 64, 1), blk, 0, stream>>>(
      bufP, w_ff1b, ff1_b2, x, bufX, CINNER, CINNER, CD, CINNER, 0.5f, 0, 0, 0);

  // ---- Attention ----
  ln_k<1><<<dim3(CBT), blk, 0, stream>>>(bufX, attn_lng, attn_lnb, bufH);
  gemm_bf<128, 128, EPI_BF><<<dim3(4, 64, 1), blk, 0, stream>>>(
      bufH, w_q, nullptr, nullptr, bufQ, CD, CD, CD, CD, 1.0f, 0, 0, 0);
  gemm_bf<128, 128, EPI_BF><<<dim3(4, 64, 1), blk, 0, stream>>>(
      bufH, w_k, nullptr, nullptr, bufK, CD, CD, CD, CD, 1.0f, 0, 0, 0);
  gemm_bf<128, 128, EPI_BF><<<dim3(4, 64, 1), blk, 0, stream>>>(
      bufH, w_v, nullptr, nullptr, bufV, CD, CD, CD, CD, 1.0f, 0, 0, 0);
  rope_k<<<dim3(CB * CT * 256 / 256), blk, 0, stream>>>(
      (unsigned*)bufQ, (unsigned*)bufK, cosT, sinT);
  vtrans_k<<<dim3(CT / 64, CB * CH), blk, 0, stream>>>((const u16*)bufV, (u16*)bufVT);

  const long SZ = (long)CT * CT;            // per-(b,h) score elements
  for (int zc = 0; zc < 4; ++zc) {          // zc = batch index (8 heads each)
    const bf16_t* Qb = bufQ + (long)zc * TDE;
    const bf16_t* Kb = bufK + (long)zc * TDE;
    // S = Q @ K^T * 0.125 (bf16 out), z = head
    gemm_bf<128, 128, EPI_BF><<<dim3(16, 16, 8), blk, 0, stream>>>(
        Qb, Kb, nullptr, nullptr, bufP, CD, CD, CT, CDH, 0.125f, 64, 64, SZ);
    softmax_k<<<dim3(8 * CT), blk, 0, stream>>>((u16*)bufP);
    // O = P @ V  (B = VT[bh][d][t], BROW)
    gemm_bf<64, 64, EPI_BF><<<dim3(1, 32, 8), blk, 0, stream>>>(
        bufP, bufVT + (long)zc * 8 * CDH * CT, nullptr, nullptr,
        bufO + (long)zc * TDE, CT, CT, CD, CT, 1.0f, SZ, (long)CDH * CT, 64);
  }
  gemm_bf<128, 128, EPI_RES><<<dim3(4, 64, 1), blk, 0, stream>>>(
      bufO, w_o, nullptr, bufX, bufX, CD, CD, CD, CD, 1.0f, 0, 0, 0);

  // ---- Conv module ----
  ln_k<1><<<dim3(CBT), blk, 0, stream>>>(bufX, conv_lng, conv_lnb, bufH);
  gemm_bf<128, 128, EPI_BF><<<dim3(8, 64, 1), blk, 0, stream>>>(
      bufH, w_pw1, pw1_b, nullptr, bufP, CD, CD, 2 * CD, CD, 1.0f, 0, 0, 0);
  glu_k<<<dim3(CBT * 128 / 256), blk, 0, stream>>>((const u16*)bufP, (u16*)bufH);
  dwconv_k<<<dim3(512), blk, 0, stream>>>((const u16*)bufH, dwT, dw_b, bufC);
  bn_part_k<<<dim3(64), blk, 0, stream>>>(bufC, psum, psq);
  bn_fin_k<<<dim3(2), blk, 0, stream>>>(psum, psq, stat);
  bn_app_k<<<dim3(CBT * CD / 256), blk, 0, stream>>>(bufC, stat, bn_g, bn_b, (u16*)bufH);
  gemm_bf<128, 128, EPI_RES><<<dim3(4, 64, 1), blk, 0, stream>>>(
      bufH, w_pw2, pw2_b, bufX, bufX, CD, CD, CD, CD, 1.0f, 0, 0, 0);

  // ---- FF2 ----
  ln_k<1><<<dim3(CBT), blk, 0, stream>>>(bufX, ff2_lng, ff2_lnb, bufH);
  gemm_bf<128, 128, EPI_SILU_BF><<<dim3(16, 64, 1), blk, 0, stream>>>(
      bufH, w_ff2a, ff2_b1, nullptr, bufP, CD, CD, CINNER, CD, 1.0f, 0, 0, 0);
  gemm_bf<128, 128, EPI_RES><<<dim3(4, 64, 1), blk, 0, stream>>>(
      bufP, w_ff2b, ff2_b2, bufX, bufX, CINNER, CINNER, CD, CINNER, 0.5f, 0, 0, 0);

  // ---- Output LN (f32 out) ----
  ln_k<0><<<dim3(CBT), blk, 0, stream>>>(bufX, out_lng, out_lnb, out);

  (void)in_sizes; (void)n_in; (void)out_size; (void)ws_size;
}

// Round 3
// 493.449 us; speedup vs baseline: 3.3126x; 1.4564x over previous
//
#include <hip/hip_runtime.h>

// ---------------------------------------------------------------------------
// STTConformerBlock: B=4 T=2048 D=512 H=8 DH=64 INNER=2048 K=31, f32 I/O.
// bf16 MFMA GEMMs (B pre-transposed [N][K]), global_load_lds staging with
// XOR bank swizzle (pre-swizzled global source, swizzled ds_read), flash attn.
// ---------------------------------------------------------------------------

typedef float  f32x4  __attribute__((ext_vector_type(4)));
typedef __bf16 bf16_t;
typedef __bf16 bf16x8 __attribute__((ext_vector_type(8)));
typedef unsigned short u16;
typedef unsigned short u16x4 __attribute__((ext_vector_type(4)));
typedef unsigned short u16x8 __attribute__((ext_vector_type(8)));

#define DEVI __device__ __forceinline__

static constexpr int CB = 4, CT = 2048, CD = 512, CH = 8, CDH = 64, CINNER = 2048, CK = 31;
static constexpr int CBT = CB * CT;
static constexpr long TDE = (long)CT * CD;

DEVI u16 f2bf(float f) {
  unsigned u = __builtin_bit_cast(unsigned, f);
  u += 0x7FFFu + ((u >> 16) & 1u);
  return (u16)(u >> 16);
}
DEVI float bf2f(u16 h) { return __builtin_bit_cast(float, (unsigned)h << 16); }
DEVI float sigm(float x) { return 1.0f / (1.0f + __expf(-x)); }

DEVI void gload16(const bf16_t* g, bf16_t* l) {
  __builtin_amdgcn_global_load_lds(
      (const __attribute__((address_space(1))) unsigned int*)g,
      (__attribute__((address_space(3))) unsigned int*)l, 16, 0, 0);
}

enum { EPI_BF = 0, EPI_SILU_BF = 1, EPI_RES = 2 };

// ---------------------------------------------------------------------------
// bf16 GEMM: C[M,N] = epi( A[M,K] @ B[N,K]^T * scale + bias )
// LDS tiles [rows][64] bf16, XOR-swizzled in 16B chunks: phys_c = c ^ (row&7).
// Staged by gload_lds with linear dest + pre-swizzled global source.
// ---------------------------------------------------------------------------
template<int BM, int BN, int EPI>
__global__ __launch_bounds__(256) void gemm_bf(
    const bf16_t* __restrict__ A, const bf16_t* __restrict__ B,
    const float* __restrict__ bias, const float* __restrict__ res,
    void* __restrict__ Cv,
    int lda, int ldb, int ldc, int Kd, float scale,
    long sA, long sB, long sC)
{
  __shared__ __align__(16) bf16_t As[BM * 64];
  __shared__ __align__(16) bf16_t Bs[BN * 64];

  const long z = blockIdx.z;
  A += z * sA;
  B += z * sB;
  const long oC = z * sC;

  const int m0 = blockIdx.y * BM, n0 = blockIdx.x * BN;
  const int tid = threadIdx.x;
  const int wid = tid >> 6, lane = tid & 63;
  const int lrow = lane & 15, lk = lane >> 4;
  constexpr int FM = BM / 32, FN = BN / 32;
  const int wm = (wid >> 1) * (BM / 2), wn = (wid & 1) * (BN / 2);
  const int r8 = tid >> 3;
  const int cs = (((tid & 7) ^ (r8 & 7)) << 3);   // swizzled source chunk
  const int fsw = lrow & 7;                        // frag-read swizzle

  f32x4 acc[FM][FN] = {};

  for (int k0 = 0; k0 < Kd; k0 += 64) {
    const bf16_t* ga = A + (long)(m0 + r8) * lda + (k0 + cs);
    const bf16_t* gb = B + (long)(n0 + r8) * ldb + (k0 + cs);
#pragma unroll
    for (int it = 0; it < BM / 32; ++it)
      gload16(ga + (long)it * 32 * lda, &As[tid * 8 + it * 2048]);
#pragma unroll
    for (int it = 0; it < BN / 32; ++it)
      gload16(gb + (long)it * 32 * ldb, &Bs[tid * 8 + it * 2048]);
    __syncthreads();

    bf16x8 av[2][FM], bv[2][FN];
#pragma unroll
    for (int kk = 0; kk < 2; ++kk) {
#pragma unroll
      for (int i = 0; i < FM; ++i)
        av[kk][i] = *(const bf16x8*)&As[(wm + i * 16 + lrow) * 64 + ((((kk << 2) + lk) ^ fsw) << 3)];
#pragma unroll
      for (int j = 0; j < FN; ++j)
        bv[kk][j] = *(const bf16x8*)&Bs[(wn + j * 16 + lrow) * 64 + ((((kk << 2) + lk) ^ fsw) << 3)];
    }
#pragma unroll
    for (int kk = 0; kk < 2; ++kk)
#pragma unroll
      for (int i = 0; i < FM; ++i)
#pragma unroll
        for (int j = 0; j < FN; ++j)
          acc[i][j] = __builtin_amdgcn_mfma_f32_16x16x32_bf16(av[kk][i], bv[kk][j], acc[i][j], 0, 0, 0);
    __syncthreads();
  }

#pragma unroll
  for (int j = 0; j < FN; ++j) {
    int col = n0 + wn + j * 16 + lrow;
    float bb = bias ? bias[col] : 0.0f;
#pragma unroll
    for (int i = 0; i < FM; ++i) {
#pragma unroll
      for (int r = 0; r < 4; ++r) {
        int row = m0 + wm + i * 16 + lk * 4 + r;
        long idx = oC + (long)row * ldc + col;
        float v = (acc[i][j][r] + bb) * scale;
        if constexpr (EPI == EPI_SILU_BF) v *= sigm(v);
        if constexpr (EPI == EPI_RES) {
          ((float*)Cv)[idx] = res[idx] + v;
        } else {
          ((bf16_t*)Cv)[idx] = (bf16_t)v;
        }
      }
    }
  }
}

// ---------------------------------------------------------------------------
// Flash attention: one block = 128 q-rows of one (b,h). 4 waves, wave owns
// 32 q-rows (all online-softmax stats wave-local). KV tiles of 128.
// LDS (64 KB): P[128][128] (bf16, swizzled; first half aliases Q staging),
// K[128][64], VT-tile[64][128].
// ---------------------------------------------------------------------------
__global__ __launch_bounds__(256) void fattn_k(
    const bf16_t* __restrict__ QK,   // bufQKV [B*T][1536], Q at 0, K at 512
    const bf16_t* __restrict__ VT,   // [B*H][64][2048]
    bf16_t* __restrict__ O)          // [B*T][512]
{
  __shared__ __align__(16) u16 smem[32768];      // 64 KB
  bf16_t* SP = (bf16_t*)smem;                    // P tile (32 KB), aliases Q
  bf16_t* SK = (bf16_t*)(smem + 16384);          // K tile (16 KB)
  bf16_t* SV = (bf16_t*)(smem + 24576);          // VT tile (16 KB)
  u16*    PU = smem;

  const int q0 = blockIdx.x * 128;
  const int bh = blockIdx.y, b = bh >> 3, h = bh & 7;
  const bf16_t* Qb = QK + ((long)b * CT + q0) * 1536 + h * 64;
  const bf16_t* Kb = QK + (long)b * CT * 1536 + 512 + h * 64;
  const bf16_t* Vb = VT + (long)bh * (64 * 2048);

  const int tid = threadIdx.x;
  const int w = tid >> 6, lane = tid & 63;
  const int lrow = lane & 15, lk = lane >> 4;
  const int fsw = lrow & 7;
  const int r8 = tid >> 3;
  const int cs8 = (((tid & 7) ^ (r8 & 7)) << 3);   // 8-chunk swizzled src (K/Q)
  const int rv = tid >> 4;
  const int cv16 = ((tid & 15) ^ (rv & 7)) << 3;   // 16-chunk swizzled src (V)

  // ---- stage Q (into SP region), load Q fragments, then SP is free for P ----
#pragma unroll
  for (int it = 0; it < 4; ++it)
    gload16(Qb + (long)(r8 + it * 32) * 1536 + cs8, (bf16_t*)smem + tid * 8 + it * 2048);
  __syncthreads();

  bf16x8 qf[2][2];   // [kk][i]
#pragma unroll
  for (int kk = 0; kk < 2; ++kk)
#pragma unroll
    for (int i = 0; i < 2; ++i)
      qf[kk][i] = *(const bf16x8*)&((bf16_t*)smem)[(w * 32 + i * 16 + lrow) * 64 + ((((kk << 2) + lk) ^ fsw) << 3)];

  f32x4 oacc[2][4] = {};
  float mrun[2][4], lrun[2][4];
#pragma unroll
  for (int i = 0; i < 2; ++i)
#pragma unroll
    for (int r = 0; r < 4; ++r) { mrun[i][r] = -3.0e38f; lrun[i][r] = 0.0f; }

  for (int kv0 = 0; kv0 < CT; kv0 += 128) {
    // stage K tile [128][64] and VT tile [64][128]
#pragma unroll
    for (int it = 0; it < 4; ++it)
      gload16(Kb + (long)(kv0 + r8 + it * 32) * 1536 + cs8, SK + tid * 8 + it * 2048);
#pragma unroll
    for (int it = 0; it < 4; ++it)
      gload16(Vb + (long)(rv + it * 16) * 2048 + kv0 + cv16, SV + tid * 8 + it * 2048);
    __syncthreads();

    // S = Q @ K^T
    f32x4 s[2][8] = {};
#pragma unroll
    for (int j = 0; j < 8; ++j) {
      bf16x8 kf0 = *(const bf16x8*)&SK[(j * 16 + lrow) * 64 + ((lk ^ fsw) << 3)];
      bf16x8 kf1 = *(const bf16x8*)&SK[(j * 16 + lrow) * 64 + (((4 + lk) ^ fsw) << 3)];
      s[0][j] = __builtin_amdgcn_mfma_f32_16x16x32_bf16(qf[0][0], kf0, s[0][j], 0, 0, 0);
      s[1][j] = __builtin_amdgcn_mfma_f32_16x16x32_bf16(qf[0][1], kf0, s[1][j], 0, 0, 0);
      s[0][j] = __builtin_amdgcn_mfma_f32_16x16x32_bf16(qf[1][0], kf1, s[0][j], 0, 0, 0);
      s[1][j] = __builtin_amdgcn_mfma_f32_16x16x32_bf16(qf[1][1], kf1, s[1][j], 0, 0, 0);
    }

    // online softmax (rows wave-local; stats replicated over lrow lanes)
#pragma unroll
    for (int i = 0; i < 2; ++i)
#pragma unroll
      for (int j = 0; j < 8; ++j)
#pragma unroll
        for (int r = 0; r < 4; ++r) s[i][j][r] *= 0.125f;

    float al[2][4];
#pragma unroll
    for (int i = 0; i < 2; ++i) {
#pragma unroll
      for (int r = 0; r < 4; ++r) {
        float m = s[i][0][r];
#pragma unroll
        for (int j = 1; j < 8; ++j) m = fmaxf(m, s[i][j][r]);
        m = fmaxf(m, __shfl_xor(m, 1)); m = fmaxf(m, __shfl_xor(m, 2));
        m = fmaxf(m, __shfl_xor(m, 4)); m = fmaxf(m, __shfl_xor(m, 8));
        float mn = fmaxf(mrun[i][r], m);
        al[i][r] = __expf(mrun[i][r] - mn);
        mrun[i][r] = mn;
      }
    }
#pragma unroll
    for (int i = 0; i < 2; ++i) {
#pragma unroll
      for (int r = 0; r < 4; ++r) {
        float ps = 0.0f;
#pragma unroll
        for (int j = 0; j < 8; ++j) {
          float pv = __expf(s[i][j][r] - mrun[i][r]);
          s[i][j][r] = pv;
          ps += pv;
        }
        ps += __shfl_xor(ps, 1); ps += __shfl_xor(ps, 2);
        ps += __shfl_xor(ps, 4); ps += __shfl_xor(ps, 8);
        lrun[i][r] = lrun[i][r] * al[i][r] + ps;
      }
    }
    // rescale O
#pragma unroll
    for (int i = 0; i < 2; ++i)
#pragma unroll
      for (int j = 0; j < 4; ++j)
#pragma unroll
        for (int r = 0; r < 4; ++r) oacc[i][j][r] *= al[i][r];

    // write P tile (bf16, swizzled), rows are wave-private
#pragma unroll
    for (int i = 0; i < 2; ++i) {
#pragma unroll
      for (int r = 0; r < 4; ++r) {
        int row = w * 32 + i * 16 + lk * 4 + r;
        int rs = row & 7;
        u16* pr = PU + row * 128 + (lrow & 7);
        int chi = lrow >> 3;
#pragma unroll
        for (int j = 0; j < 8; ++j)
          pr[(((j << 1) + chi) ^ rs) << 3] = f2bf(s[i][j][r]);
      }
    }
    __syncthreads();

    // O += P @ V   (A = P[q][kv], B = VT[d][kv])
#pragma unroll
    for (int k2 = 0; k2 < 4; ++k2) {
      bf16x8 pa[2];
#pragma unroll
      for (int i = 0; i < 2; ++i)
        pa[i] = *(const bf16x8*)&SP[(w * 32 + i * 16 + lrow) * 128 + ((((k2 << 2) + lk) ^ fsw) << 3)];
#pragma unroll
      for (int j = 0; j < 4; ++j) {
        bf16x8 pb = *(const bf16x8*)&SV[(j * 16 + lrow) * 128 + ((((k2 << 2) + lk) ^ fsw) << 3)];
        oacc[0][j] = __builtin_amdgcn_mfma_f32_16x16x32_bf16(pa[0], pb, oacc[0][j], 0, 0, 0);
        oacc[1][j] = __builtin_amdgcn_mfma_f32_16x16x32_bf16(pa[1], pb, oacc[1][j], 0, 0, 0);
      }
    }
    __syncthreads();
  }

  // epilogue: O /= l, write bf16
  bf16_t* Ob = O + ((long)b * CT + q0) * CD + h * 64;
#pragma unroll
  for (int i = 0; i < 2; ++i) {
#pragma unroll
    for (int r = 0; r < 4; ++r) {
      float rl = 1.0f / lrun[i][r];
      int row = w * 32 + i * 16 + lk * 4 + r;
#pragma unroll
      for (int j = 0; j < 4; ++j)
        Ob[(long)row * CD + j * 16 + lrow] = (bf16_t)(oacc[i][j][r] * rl);
    }
  }
}

// ---------------------------------------------------------------------------
// Weight convert+transpose: w[K][N] f32 -> o[N][K] bf16. 64x64 tiles.
// ---------------------------------------------------------------------------
__global__ __launch_bounds__(256) void wtrans_k(
    const float* __restrict__ w, u16* __restrict__ o, int Kd, int N)
{
  __shared__ u16 lt[64][72];
  const int k0 = blockIdx.y * 64, n0 = blockIdx.x * 64;
  const int tid = threadIdx.x;
#pragma unroll
  for (int it = 0; it < 4; ++it) {
    int kk = (tid >> 4) + it * 16, nn = (tid & 15) * 4;
    float4 f = *(const float4*)(w + (long)(k0 + kk) * N + n0 + nn);
    lt[kk][nn + 0] = f2bf(f.x); lt[kk][nn + 1] = f2bf(f.y);
    lt[kk][nn + 2] = f2bf(f.z); lt[kk][nn + 3] = f2bf(f.w);
  }
  __syncthreads();
#pragma unroll
  for (int it = 0; it < 2; ++it) {
    int nn = (tid >> 3) + it * 32, kk = (tid & 7) * 8;
    u16x8 pk;
#pragma unroll
    for (int e = 0; e < 8; ++e) pk[e] = lt[kk + e][nn];
    *(u16x8*)(o + (long)(n0 + nn) * Kd + k0 + kk) = pk;
  }
}

// V columns of bufQKV -> VT[bh][d][t]
__global__ __launch_bounds__(256) void vtrans_k(
    const u16* __restrict__ v, u16* __restrict__ vt)
{
  __shared__ u16 lt[64][72];
  const int bh = blockIdx.y, b = bh >> 3, h = bh & 7;
  const int t0 = blockIdx.x * 64;
  const int tid = threadIdx.x;
#pragma unroll
  for (int it = 0; it < 2; ++it) {
    int tt = (tid >> 3) + it * 32, dd = (tid & 7) * 8;
    u16x8 vv = *(const u16x8*)(v + ((long)b * CT + t0 + tt) * 1536 + 1024 + h * 64 + dd);
#pragma unroll
    for (int e = 0; e < 8; ++e) lt[tt][dd + e] = vv[e];
  }
  __syncthreads();
#pragma unroll
  for (int it = 0; it < 2; ++it) {
    int dd = (tid >> 3) + it * 32, tt = (tid & 7) * 8;
    u16x8 pk;
#pragma unroll
    for (int e = 0; e < 8; ++e) pk[e] = lt[tt + e][dd];
    *(u16x8*)(vt + ((long)bh * 64 + dd) * CT + t0 + tt) = pk;
  }
}

// dw_w[512][31] f32 -> wT[31][512] f32
__global__ void dwt_k(const float* __restrict__ w, float* __restrict__ o)
{
  int i = blockIdx.x * 256 + threadIdx.x;
  if (i < 512 * 31) { int c = i / 31, k = i % 31; o[k * 512 + c] = w[i]; }
}

// ---------------------------------------------------------------------------
// LayerNorm over D=512, one block per row.
// ---------------------------------------------------------------------------
template<int OBF>
__global__ __launch_bounds__(256) void ln_k(
    const float* __restrict__ in, const float* __restrict__ g,
    const float* __restrict__ b, void* __restrict__ out)
{
  __shared__ float rs[4], rq[4];
  const long row = blockIdx.x;
  const int tid = threadIdx.x;
  float2 v = ((const float2*)(in + row * CD))[tid];
  float s = v.x + v.y, q = v.x * v.x + v.y * v.y;
#pragma unroll
  for (int o = 32; o; o >>= 1) { s += __shfl_xor(s, o); q += __shfl_xor(q, o); }
  if ((tid & 63) == 0) { rs[tid >> 6] = s; rq[tid >> 6] = q; }
  __syncthreads();
  s = rs[0] + rs[1] + rs[2] + rs[3];
  q = rq[0] + rq[1] + rq[2] + rq[3];
  float mean = s * (1.0f / CD);
  float var = q * (1.0f / CD) - mean * mean;
  float rstd = rsqrtf(var + 1e-5f);
  float2 gg = ((const float2*)g)[tid];
  float2 bb = ((const float2*)b)[tid];
  float ox = (v.x - mean) * rstd * gg.x + bb.x;
  float oy = (v.y - mean) * rstd * gg.y + bb.y;
  if (OBF) {
    unsigned pk = ((unsigned)f2bf(oy) << 16) | f2bf(ox);
    ((unsigned*)out)[row * 256 + tid] = pk;
  } else {
    ((float2*)out)[row * 256 + tid] = make_float2(ox, oy);
  }
}

__global__ void rope_table_k(float* __restrict__ cosT, float* __restrict__ sinT)
{
  int tid = blockIdx.x * 256 + threadIdx.x;     // T*32
  int t = tid >> 5, i = tid & 31;
  float freq = __expf(-(float)i * (9.210340371976184f / 32.0f));
  float ang = (float)t * freq;
  cosT[tid] = cosf(ang);
  sinT[tid] = sinf(ang);
}

// In-place RoPE on fused QKV buffer (Q cols 0..511, K cols 512..1023, bf16 pairs).
__global__ __launch_bounds__(256) void rope_k(
    unsigned* __restrict__ qkv,
    const float* __restrict__ cosT, const float* __restrict__ sinT)
{
  long p = (long)blockIdx.x * 256 + threadIdx.x;   // B*T*256 pair slots
  int pr = (int)(p & 255);
  long row = p >> 8;
  int t = (int)(row & (CT - 1));
  int h = pr >> 5, i = pr & 31;
  float c = cosT[t * 32 + i], s = sinT[t * 32 + i];
  unsigned* base = qkv + row * 768 + h * 32 + i;
  unsigned v = base[0];
  float xe = bf2f((u16)v), xo = bf2f((u16)(v >> 16));
  base[0] = ((unsigned)f2bf(xe * s + xo * c) << 16) | f2bf(xe * c - xo * s);
  v = base[256];
  xe = bf2f((u16)v); xo = bf2f((u16)(v >> 16));
  base[256] = ((unsigned)f2bf(xe * s + xo * c) << 16) | f2bf(xe * c - xo * s);
}

// GLU
__global__ __launch_bounds__(256) void glu_k(
    const u16* __restrict__ t, u16* __restrict__ out)
{
  long idx = (long)blockIdx.x * 256 + threadIdx.x;  // BT*128
  long row = idx >> 7;
  int c4 = (int)(idx & 127) * 4;
  u16x4 a = *(const u16x4*)(t + row * 1024 + c4);
  u16x4 b = *(const u16x4*)(t + row * 1024 + 512 + c4);
  u16x4 o;
#pragma unroll
  for (int e = 0; e < 4; ++e) o[e] = f2bf(bf2f(a[e]) * sigm(bf2f(b[e])));
  *(u16x4*)(out + row * CD + c4) = o;
}

// Depthwise conv1d: bf16 in, f32 out. 8 t-outputs x 4 channels/thread.
__global__ __launch_bounds__(256) void dwconv_k(
    const u16* __restrict__ in, const float* __restrict__ wT,
    const float* __restrict__ wb, float* __restrict__ out)
{
  long idx = (long)blockIdx.x * 256 + threadIdx.x;  // B*(T/8)*(D/4)
  int c4 = (int)(idx & 127) * 4;
  int t0 = (int)((idx >> 7) & 255) * 8;
  int b = (int)(idx >> 15);
  const u16* base = in + (long)b * CT * CD;
  float4 bias = *(const float4*)(wb + c4);
  float4 acc[8];
#pragma unroll
  for (int t = 0; t < 8; ++t) acc[t] = bias;
#pragma unroll
  for (int j = 0; j < 38; ++j) {
    int tr = t0 + j - 15;
    float4 row = make_float4(0.f, 0.f, 0.f, 0.f);
    if (tr >= 0 && tr < CT) {
      u16x4 rv = *(const u16x4*)(base + (long)tr * CD + c4);
      row = make_float4(bf2f(rv[0]), bf2f(rv[1]), bf2f(rv[2]), bf2f(rv[3]));
    }
#pragma unroll
    for (int t = 0; t < 8; ++t) {
      int k = j - t;
      if (k >= 0 && k < CK) {
        float4 w4 = *(const float4*)(wT + k * CD + c4);
        acc[t].x += row.x * w4.x; acc[t].y += row.y * w4.y;
        acc[t].z += row.z * w4.z; acc[t].w += row.w * w4.w;
      }
    }
  }
#pragma unroll
  for (int t = 0; t < 8; ++t)
    *(float4*)(out + ((long)b * CT + t0 + t) * CD + c4) = acc[t];
}

__global__ __launch_bounds__(256) void bn_part_k(
    const float* __restrict__ in, float* __restrict__ psum, float* __restrict__ psq)
{
  const int blk = blockIdx.x;        // 64
  const int tid = threadIdx.x;
  const int c0 = tid, c1 = tid + 256;
  const int rows = CBT / 64;
  const float* base = in + (long)blk * rows * CD;
  float s0 = 0, q0 = 0, s1 = 0, q1 = 0;
  for (int r = 0; r < rows; ++r) {
    float v0 = base[(long)r * CD + c0]; s0 += v0; q0 += v0 * v0;
    float v1 = base[(long)r * CD + c1]; s1 += v1; q1 += v1 * v1;
  }
  psum[blk * CD + c0] = s0; psq[blk * CD + c0] = q0;
  psum[blk * CD + c1] = s1; psq[blk * CD + c1] = q1;
}

__global__ __launch_bounds__(256) void bn_fin_k(
    const float* __restrict__ psum, const float* __restrict__ psq,
    float* __restrict__ stat)
{
  int c = blockIdx.x * 256 + threadIdx.x;
  float s = 0, q = 0;
  for (int i = 0; i < 64; ++i) { s += psum[i * CD + c]; q += psq[i * CD + c]; }
  float mean = s * (1.0f / CBT);
  float var = q * (1.0f / CBT) - mean * mean;
  stat[c] = mean;
  stat[CD + c] = rsqrtf(var + 1e-5f);
}

__global__ __launch_bounds__(256) void bn_app_k(
    const float* __restrict__ h, const float* __restrict__ stat,
    const float* __restrict__ g, const float* __restrict__ b,
    u16* __restrict__ out)
{
  long idx = (long)blockIdx.x * 256 + threadIdx.x;
  int c = (int)(idx & 511);
  float v = (h[idx] - stat[c]) * stat[CD + c] * g[c] + b[c];
  v = v * sigm(v);
  out[idx] = f2bf(v);
}

// ---------------------------------------------------------------------------
// Host launcher
// ---------------------------------------------------------------------------
extern "C" void kernel_launch(void* const* d_in, const int* in_sizes, int n_in,
                              void* d_out, int out_size, void* d_ws, size_t ws_size,
                              hipStream_t stream)
{
  const float* x        = (const float*)d_in[0];
  const float* ff1_lng  = (const float*)d_in[1];
  const float* ff1_lnb  = (const float*)d_in[2];
  const float* ff1_w1   = (const float*)d_in[3];
  const float* ff1_b1   = (const float*)d_in[4];
  const float* ff1_w2   = (const float*)d_in[5];
  const float* ff1_b2   = (const float*)d_in[6];
  const float* attn_lng = (const float*)d_in[7];
  const float* attn_lnb = (const float*)d_in[8];
  const float* wq       = (const float*)d_in[9];
  const float* wk       = (const float*)d_in[10];
  const float* wv       = (const float*)d_in[11];
  const float* wo       = (const float*)d_in[12];
  const float* conv_lng = (const float*)d_in[13];
  const float* conv_lnb = (const float*)d_in[14];
  const float* pw1_w    = (const float*)d_in[15];
  const float* pw1_b    = (const float*)d_in[16];
  const float* dw_w     = (const float*)d_in[17];
  const float* dw_b     = (const float*)d_in[18];
  const float* bn_g     = (const float*)d_in[19];
  const float* bn_b     = (const float*)d_in[20];
  const float* pw2_w    = (const float*)d_in[21];
  const float* pw2_b    = (const float*)d_in[22];
  const float* ff2_lng  = (const float*)d_in[23];
  const float* ff2_lnb  = (const float*)d_in[24];
  const float* ff2_w1   = (const float*)d_in[25];
  const float* ff2_b1   = (const float*)d_in[26];
  const float* ff2_w2   = (const float*)d_in[27];
  const float* ff2_b2   = (const float*)d_in[28];
  const float* out_lng  = (const float*)d_in[29];
  const float* out_lnb  = (const float*)d_in[30];
  float* out = (float*)d_out;

  char* p = (char*)d_ws;
  auto alloc = [&](size_t bytes) { char* r = p; p += (bytes + 255) & ~(size_t)255; return r; };
  float*  bufX   = (float*)alloc((size_t)CBT * CD * 4);        // residual f32
  float*  bufC   = (float*)alloc((size_t)CBT * CD * 4);        // conv f32
  bf16_t* bufH   = (bf16_t*)alloc((size_t)CBT * CD * 2);       // LN/GLU/BN out
  bf16_t* bufQKV = (bf16_t*)alloc((size_t)CBT * 1536 * 2);     // fused QKV
  bf16_t* bufO   = (bf16_t*)alloc((size_t)CBT * CD * 2);       // attn out
  bf16_t* bufVT  = (bf16_t*)alloc((size_t)CBT * CD * 2);       // [bh][d][t]
  bf16_t* bufP   = (bf16_t*)alloc((size_t)CBT * CINNER * 2);   // FF hidden / pw1 out
  bf16_t* w_ff1a = (bf16_t*)alloc((size_t)CD * CINNER * 2);
  bf16_t* w_ff1b = (bf16_t*)alloc((size_t)CD * CINNER * 2);
  bf16_t* w_qkv  = (bf16_t*)alloc((size_t)CD * 1536 * 2);
  bf16_t* w_o    = (bf16_t*)alloc((size_t)CD * CD * 2);
  bf16_t* w_pw1  = (bf16_t*)alloc((size_t)CD * 2 * CD * 2);
  bf16_t* w_pw2  = (bf16_t*)alloc((size_t)CD * CD * 2);
  bf16_t* w_ff2a = (bf16_t*)alloc((size_t)CD * CINNER * 2);
  bf16_t* w_ff2b = (bf16_t*)alloc((size_t)CD * CINNER * 2);
  float* dwT  = (float*)alloc((size_t)CK * CD * 4);
  float* cosT = (float*)alloc((size_t)CT * 32 * 4);
  float* sinT = (float*)alloc((size_t)CT * 32 * 4);
  float* psum = (float*)alloc((size_t)64 * CD * 4);
  float* psq  = (float*)alloc((size_t)64 * CD * 4);
  float* stat = (float*)alloc((size_t)2 * CD * 4);

  const dim3 blk(256);

  // ---- prep: weight transposes (QKV fused), RoPE table ----
  wtrans_k<<<dim3(CINNER / 64, CD / 64), blk, 0, stream>>>(ff1_w1, (u16*)w_ff1a, CD, CINNER);
  wtrans_k<<<dim3(CD / 64, CINNER / 64), blk, 0, stream>>>(ff1_w2, (u16*)w_ff1b, CINNER, CD);
  wtrans_k<<<dim3(CD / 64, CD / 64), blk, 0, stream>>>(wq, (u16*)w_qkv, CD, CD);
  wtrans_k<<<dim3(CD / 64, CD / 64), blk, 0, stream>>>(wk, (u16*)(w_qkv + (size_t)512 * CD), CD, CD);
  wtrans_k<<<dim3(CD / 64, CD / 64), blk, 0, stream>>>(wv, (u16*)(w_qkv + (size_t)1024 * CD), CD, CD);
  wtrans_k<<<dim3(CD / 64, CD / 64), blk, 0, stream>>>(wo, (u16*)w_o, CD, CD);
  wtrans_k<<<dim3(2 * CD / 64, CD / 64), blk, 0, stream>>>(pw1_w, (u16*)w_pw1, CD, 2 * CD);
  wtrans_k<<<dim3(CD / 64, CD / 64), blk, 0, stream>>>(pw2_w, (u16*)w_pw2, CD, CD);
  wtrans_k<<<dim3(CINNER / 64, CD / 64), blk, 0, stream>>>(ff2_w1, (u16*)w_ff2a, CD, CINNER);
  wtrans_k<<<dim3(CD / 64, CINNER / 64), blk, 0, stream>>>(ff2_w2, (u16*)w_ff2b, CINNER, CD);
  dwt_k<<<dim3(62), blk, 0, stream>>>(dw_w, dwT);
  rope_table_k<<<dim3(CT * 32 / 256), blk, 0, stream>>>(cosT, sinT);

  // ---- FF1 ----
  ln_k<1><<<dim3(CBT), blk, 0, stream>>>(x, ff1_lng, ff1_lnb, bufH);
  gemm_bf<128, 128, EPI_SILU_BF><<<dim3(16, 64, 1), blk, 0, stream>>>(
      bufH, w_ff1a, ff1_b1, nullptr, bufP, CD, CD, CINNER, CD, 1.0f, 0, 0, 0);
  gemm_bf<64, 128, EPI_RES><<<dim3(4, 128, 1), blk, 0, stream>>>(
      bufP, w_ff1b, ff1_b2, x, bufX, CINNER, CINNER, CD, CINNER, 0.5f, 0, 0, 0);

  // ---- Attention ----
  ln_k<1><<<dim3(CBT), blk, 0, stream>>>(bufX, attn_lng, attn_lnb, bufH);
  gemm_bf<128, 128, EPI_BF><<<dim3(12, 64, 1), blk, 0, stream>>>(
      bufH, w_qkv, nullptr, nullptr, bufQKV, CD, CD, 1536, CD, 1.0f, 0, 0, 0);
  rope_k<<<dim3(CB * CT), blk, 0, stream>>>((unsigned*)bufQKV, cosT, sinT);
  vtrans_k<<<dim3(CT / 64, CB * CH), blk, 0, stream>>>((const u16*)bufQKV, (u16*)bufVT);
  fattn_k<<<dim3(CT / 128, CB * CH), blk, 0, stream>>>(bufQKV, bufVT, bufO);
  gemm_bf<64, 128, EPI_RES><<<dim3(4, 128, 1), blk, 0, stream>>>(
      bufO, w_o, nullptr, bufX, bufX, CD, CD, CD, CD, 1.0f, 0, 0, 0);

  // ---- Conv module ----
  ln_k<1><<<dim3(CBT), blk, 0, stream>>>(bufX, conv_lng, conv_lnb, bufH);
  gemm_bf<128, 128, EPI_BF><<<dim3(8, 64, 1), blk, 0, stream>>>(
      bufH, w_pw1, pw1_b, nullptr, bufP, CD, CD, 2 * CD, CD, 1.0f, 0, 0, 0);
  glu_k<<<dim3(CBT * 128 / 256), blk, 0, stream>>>((const u16*)bufP, (u16*)bufH);
  dwconv_k<<<dim3(512), blk, 0, stream>>>((const u16*)bufH, dwT, dw_b, bufC);
  bn_part_k<<<dim3(64), blk, 0, stream>>>(bufC, psum, psq);
  bn_fin_k<<<dim3(2), blk, 0, stream>>>(psum, psq, stat);
  bn_app_k<<<dim3(CBT * CD / 256), blk, 0, stream>>>(bufC, stat, bn_g, bn_b, (u16*)bufH);
  gemm_bf<64, 128, EPI_RES><<<dim3(4, 128, 1), blk, 0, stream>>>(
      bufH, w_pw2, pw2_b, bufX, bufX, CD, CD, CD, CD, 1.0f, 0, 0, 0);

  // ---- FF2 ----
  ln_k<1><<<dim3(CBT), blk, 0, stream>>>(bufX, ff2_lng, ff2_lnb, bufH);
  gemm_bf<128, 128, EPI_SILU_BF><<<dim3(16, 64, 1), blk, 0, stream>>>(
      bufH, w_ff2a, ff2_b1, nullptr, bufP, CD, CD, CINNER, CD, 1.0f, 0, 0, 0);
  gemm_bf<64, 128, EPI_RES><<<dim3(4, 128, 1), blk, 0, stream>>>(
      bufP, w_ff2b, ff2_b2, bufX, bufX, CINNER, CINNER, CD, CINNER, 0.5f, 0, 0, 0);

  // ---- Output LN ----
  ln_k<0><<<dim3(CBT), blk, 0, stream>>>(bufX, out_lng, out_lnb, out);

  (void)in_sizes; (void)n_in; (void)out_size; (void)ws_size;
}

// Round 4
// 480.119 us; speedup vs baseline: 3.4046x; 1.0278x over previous
//
#include <hip/hip_runtime.h>

// ---------------------------------------------------------------------------
// STTConformerBlock: B=4 T=2048 D=512 H=8 DH=64 INNER=2048 K=31, f32 I/O.
// bf16 MFMA GEMMs (B pre-transposed [N][K]), global_load_lds staging with
// XOR bank swizzle. Flash attention: swapped-QK^T 32x32 MFMA, zero-LDS,
// in-register softmax (cvt_pk + permlane32_swap), exp2 domain, defer-max.
// ---------------------------------------------------------------------------

typedef float  f32x4   __attribute__((ext_vector_type(4)));
typedef float  f32x16  __attribute__((ext_vector_type(16)));
typedef __bf16 bf16_t;
typedef __bf16 bf16x8  __attribute__((ext_vector_type(8)));
typedef unsigned short u16;
typedef unsigned short u16x4 __attribute__((ext_vector_type(4)));
typedef unsigned short u16x8 __attribute__((ext_vector_type(8)));
typedef unsigned int   u32x4 __attribute__((ext_vector_type(4)));
typedef int            i32x2 __attribute__((ext_vector_type(2)));

#define DEVI __device__ __forceinline__

static constexpr int CB = 4, CT = 2048, CD = 512, CH = 8, CDH = 64, CINNER = 2048, CK = 31;
static constexpr int CBT = CB * CT;
static constexpr long TDE = (long)CT * CD;

DEVI u16 f2bf(float f) {
  unsigned u = __builtin_bit_cast(unsigned, f);
  u += 0x7FFFu + ((u >> 16) & 1u);
  return (u16)(u >> 16);
}
DEVI float bf2f(u16 h) { return __builtin_bit_cast(float, (unsigned)h << 16); }
DEVI float sigm(float x) { return 1.0f / (1.0f + __expf(-x)); }

DEVI unsigned cvtpk(float lo, float hi) {
  unsigned r;
  asm("v_cvt_pk_bf16_f32 %0, %1, %2" : "=v"(r) : "v"(lo), "v"(hi));
  return r;
}

DEVI void gload16(const bf16_t* g, bf16_t* l) {
  __builtin_amdgcn_global_load_lds(
      (const __attribute__((address_space(1))) unsigned int*)g,
      (__attribute__((address_space(3))) unsigned int*)l, 16, 0, 0);
}

enum { EPI_BF = 0, EPI_SILU_BF = 1, EPI_RES = 2 };

// ---------------------------------------------------------------------------
// bf16 GEMM: C[M,N] = epi( A[M,K] @ B[N,K]^T * scale + bias )
// ---------------------------------------------------------------------------
template<int BM, int BN, int EPI>
__global__ __launch_bounds__(256) void gemm_bf(
    const bf16_t* __restrict__ A, const bf16_t* __restrict__ B,
    const float* __restrict__ bias, const float* __restrict__ res,
    void* __restrict__ Cv,
    int lda, int ldb, int ldc, int Kd, float scale,
    long sA, long sB, long sC)
{
  __shared__ __align__(16) bf16_t As[BM * 64];
  __shared__ __align__(16) bf16_t Bs[BN * 64];

  const long z = blockIdx.z;
  A += z * sA;
  B += z * sB;
  const long oC = z * sC;

  const int m0 = blockIdx.y * BM, n0 = blockIdx.x * BN;
  const int tid = threadIdx.x;
  const int wid = tid >> 6, lane = tid & 63;
  const int lrow = lane & 15, lk = lane >> 4;
  constexpr int FM = BM / 32, FN = BN / 32;
  const int wm = (wid >> 1) * (BM / 2), wn = (wid & 1) * (BN / 2);
  const int r8 = tid >> 3;
  const int cs = (((tid & 7) ^ (r8 & 7)) << 3);
  const int fsw = lrow & 7;

  f32x4 acc[FM][FN] = {};

  for (int k0 = 0; k0 < Kd; k0 += 64) {
    const bf16_t* ga = A + (long)(m0 + r8) * lda + (k0 + cs);
    const bf16_t* gb = B + (long)(n0 + r8) * ldb + (k0 + cs);
#pragma unroll
    for (int it = 0; it < BM / 32; ++it)
      gload16(ga + (long)it * 32 * lda, &As[tid * 8 + it * 2048]);
#pragma unroll
    for (int it = 0; it < BN / 32; ++it)
      gload16(gb + (long)it * 32 * ldb, &Bs[tid * 8 + it * 2048]);
    __syncthreads();

    bf16x8 av[2][FM], bv[2][FN];
#pragma unroll
    for (int kk = 0; kk < 2; ++kk) {
#pragma unroll
      for (int i = 0; i < FM; ++i)
        av[kk][i] = *(const bf16x8*)&As[(wm + i * 16 + lrow) * 64 + ((((kk << 2) + lk) ^ fsw) << 3)];
#pragma unroll
      for (int j = 0; j < FN; ++j)
        bv[kk][j] = *(const bf16x8*)&Bs[(wn + j * 16 + lrow) * 64 + ((((kk << 2) + lk) ^ fsw) << 3)];
    }
#pragma unroll
    for (int kk = 0; kk < 2; ++kk)
#pragma unroll
      for (int i = 0; i < FM; ++i)
#pragma unroll
        for (int j = 0; j < FN; ++j)
          acc[i][j] = __builtin_amdgcn_mfma_f32_16x16x32_bf16(av[kk][i], bv[kk][j], acc[i][j], 0, 0, 0);
    __syncthreads();
  }

#pragma unroll
  for (int j = 0; j < FN; ++j) {
    int col = n0 + wn + j * 16 + lrow;
    float bb = bias ? bias[col] : 0.0f;
#pragma unroll
    for (int i = 0; i < FM; ++i) {
#pragma unroll
      for (int r = 0; r < 4; ++r) {
        int row = m0 + wm + i * 16 + lk * 4 + r;
        long idx = oC + (long)row * ldc + col;
        float v = (acc[i][j][r] + bb) * scale;
        if constexpr (EPI == EPI_SILU_BF) v *= sigm(v);
        if constexpr (EPI == EPI_RES) {
          ((float*)Cv)[idx] = res[idx] + v;
        } else {
          ((bf16_t*)Cv)[idx] = (bf16_t)v;
        }
      }
    }
  }
}

// ---------------------------------------------------------------------------
// Flash attention, swapped-QK^T 32x32 structure. 4 waves/block, each wave
// owns 32 q-rows of one (b,h). No LDS, no barriers. Q pre-scaled by
// 0.125*log2(e) at RoPE; softmax in exp2 domain with defer-max (THR=8).
//   S^T = mfma(A=K_frag, B=Q_frag): lane q = lane&31, kv over regs/halves
//   P^T packed to bf16 via v_cvt_pk_bf16_f32 + v_permlane32_swap_b32
//   O^T = mfma(A=VT_frag, B=P^T_frag): lane q = lane&31 (rescale lane-uniform)
// ---------------------------------------------------------------------------
__global__ __launch_bounds__(256) void fattn_k(
    const bf16_t* __restrict__ QK,   // [B*T][1536], Q at 0, K at 512
    const bf16_t* __restrict__ VT,   // [B*H][64][2048]
    bf16_t* __restrict__ O)          // [B*T][512]
{
  const int w = threadIdx.x >> 6, lane = threadIdx.x & 63;
  const int q0 = blockIdx.x * 128 + w * 32;
  const int bh = blockIdx.y, b = bh >> 3, h = bh & 7;
  const int l31 = lane & 31, hi = lane >> 5;

  const bf16_t* Qp = QK + ((long)b * CT + q0 + l31) * 1536 + h * 64 + hi * 8;
  const bf16_t* Kp = QK + ((long)b * CT + l31) * 1536 + 512 + h * 64 + hi * 8;
  const bf16_t* Vp = VT + ((long)bh * 64 + l31) * 2048 + hi * 8;

  bf16x8 qb[4];
#pragma unroll
  for (int m = 0; m < 4; ++m) qb[m] = *(const bf16x8*)(Qp + m * 16);

  f32x16 o0 = {}, o1 = {};
  float mrun = -3.0e38f, lrun = 0.0f;

  for (int kv0 = 0; kv0 < CT; kv0 += 64) {
    // K fragments (A-operand), direct from global
    bf16x8 ka[2][4];
#pragma unroll
    for (int j = 0; j < 2; ++j)
#pragma unroll
      for (int m = 0; m < 4; ++m)
        ka[j][m] = *(const bf16x8*)(Kp + (long)(kv0 + j * 32) * 1536 + m * 16);
    // V fragments (A-operand for PV), issued early, used after softmax
    bf16x8 va[2][4];
#pragma unroll
    for (int n = 0; n < 2; ++n)
#pragma unroll
      for (int jk = 0; jk < 4; ++jk)
        va[n][jk] = *(const bf16x8*)(Vp + (long)n * 32 * 2048 + kv0 + jk * 16);

    // S^T tiles: s0 = kv[0..31], s1 = kv[32..63]; lane q = l31
    f32x16 s0 = {}, s1 = {};
#pragma unroll
    for (int m = 0; m < 4; ++m) {
      s0 = __builtin_amdgcn_mfma_f32_32x32x16_bf16(ka[0][m], qb[m], s0, 0, 0, 0);
      s1 = __builtin_amdgcn_mfma_f32_32x32x16_bf16(ka[1][m], qb[m], s1, 0, 0, 0);
    }

    // row max: 31 in-reg fmax + 1 cross-half shuffle
    float pm = fmaxf(s0[0], s1[0]);
#pragma unroll
    for (int r = 1; r < 16; ++r) pm = fmaxf(pm, fmaxf(s0[r], s1[r]));
    pm = fmaxf(pm, __shfl_xor(pm, 32));

    if (!__all(pm <= mrun + 8.0f)) {     // defer-max: skip rescale if bounded
      float mn = fmaxf(mrun, pm);
      float al = exp2f(mrun - mn);
      mrun = mn;
      lrun *= al;
#pragma unroll
      for (int r = 0; r < 16; ++r) { o0[r] *= al; o1[r] *= al; }
    }

    float ps = 0.0f;
#pragma unroll
    for (int r = 0; r < 16; ++r) { s0[r] = exp2f(s0[r] - mrun); ps += s0[r]; }
#pragma unroll
    for (int r = 0; r < 16; ++r) { s1[r] = exp2f(s1[r] - mrun); ps += s1[r]; }
    ps += __shfl_xor(ps, 32);
    lrun += ps;

    // pack P^T -> B-operand frags: 16 cvt_pk + 8 permlane32_swap
    bf16x8 pw[4];
#pragma unroll
    for (int jk = 0; jk < 4; ++jk) {
      float e0, e1, e2, e3, e4, e5, e6, e7;
      if (jk == 0) { e0=s0[0];e1=s0[1];e2=s0[2];e3=s0[3];e4=s0[4];e5=s0[5];e6=s0[6];e7=s0[7]; }
      else if (jk == 1) { e0=s0[8];e1=s0[9];e2=s0[10];e3=s0[11];e4=s0[12];e5=s0[13];e6=s0[14];e7=s0[15]; }
      else if (jk == 2) { e0=s1[0];e1=s1[1];e2=s1[2];e3=s1[3];e4=s1[4];e5=s1[5];e6=s1[6];e7=s1[7]; }
      else { e0=s1[8];e1=s1[9];e2=s1[10];e3=s1[11];e4=s1[12];e5=s1[13];e6=s1[14];e7=s1[15]; }
      unsigned a0 = cvtpk(e0, e1), a1 = cvtpk(e2, e3);
      unsigned b0 = cvtpk(e4, e5), b1 = cvtpk(e6, e7);
      asm("v_permlane32_swap_b32 %0, %1" : "+v"(a0), "+v"(b0));
      asm("v_permlane32_swap_b32 %0, %1" : "+v"(a1), "+v"(b1));
      u32x4 t; t[0] = a0; t[1] = a1; t[2] = b0; t[3] = b1;
      pw[jk] = __builtin_bit_cast(bf16x8, t);
    }

    // O^T += VT_tile @ P^T
#pragma unroll
    for (int jk = 0; jk < 4; ++jk) {
      o0 = __builtin_amdgcn_mfma_f32_32x32x16_bf16(va[0][jk], pw[jk], o0, 0, 0, 0);
      o1 = __builtin_amdgcn_mfma_f32_32x32x16_bf16(va[1][jk], pw[jk], o1, 0, 0, 0);
    }
  }

  // epilogue: O[q][d] = O^T/l ; q = q0+l31 (lane-uniform across regs)
  float rl = 1.0f / lrun;
  bf16_t* Op = O + ((long)b * CT + q0 + l31) * CD + h * 64;
#pragma unroll
  for (int n = 0; n < 2; ++n) {
#pragma unroll
    for (int m = 0; m < 4; ++m) {
      u16x4 pk4;
#pragma unroll
      for (int e = 0; e < 4; ++e)
        pk4[e] = f2bf((n ? o1[m * 4 + e] : o0[m * 4 + e]) * rl);
      *(u16x4*)(Op + n * 32 + m * 8 + hi * 4) = pk4;
    }
  }
}

// ---------------------------------------------------------------------------
// Weight convert+transpose: w[K][N] f32 -> o[N][K] bf16. 64x64 tiles.
// ---------------------------------------------------------------------------
__global__ __launch_bounds__(256) void wtrans_k(
    const float* __restrict__ w, u16* __restrict__ o, int Kd, int N)
{
  __shared__ u16 lt[64][72];
  const int k0 = blockIdx.y * 64, n0 = blockIdx.x * 64;
  const int tid = threadIdx.x;
#pragma unroll
  for (int it = 0; it < 4; ++it) {
    int kk = (tid >> 4) + it * 16, nn = (tid & 15) * 4;
    float4 f = *(const float4*)(w + (long)(k0 + kk) * N + n0 + nn);
    lt[kk][nn + 0] = f2bf(f.x); lt[kk][nn + 1] = f2bf(f.y);
    lt[kk][nn + 2] = f2bf(f.z); lt[kk][nn + 3] = f2bf(f.w);
  }
  __syncthreads();
#pragma unroll
  for (int it = 0; it < 2; ++it) {
    int nn = (tid >> 3) + it * 32, kk = (tid & 7) * 8;
    u16x8 pk;
#pragma unroll
    for (int e = 0; e < 8; ++e) pk[e] = lt[kk + e][nn];
    *(u16x8*)(o + (long)(n0 + nn) * Kd + k0 + kk) = pk;
  }
}

// V columns of bufQKV -> VT[bh][d][t]
__global__ __launch_bounds__(256) void vtrans_k(
    const u16* __restrict__ v, u16* __restrict__ vt)
{
  __shared__ u16 lt[64][72];
  const int bh = blockIdx.y, b = bh >> 3, h = bh & 7;
  const int t0 = blockIdx.x * 64;
  const int tid = threadIdx.x;
#pragma unroll
  for (int it = 0; it < 2; ++it) {
    int tt = (tid >> 3) + it * 32, dd = (tid & 7) * 8;
    u16x8 vv = *(const u16x8*)(v + ((long)b * CT + t0 + tt) * 1536 + 1024 + h * 64 + dd);
#pragma unroll
    for (int e = 0; e < 8; ++e) lt[tt][dd + e] = vv[e];
  }
  __syncthreads();
#pragma unroll
  for (int it = 0; it < 2; ++it) {
    int dd = (tid >> 3) + it * 32, tt = (tid & 7) * 8;
    u16x8 pk;
#pragma unroll
    for (int e = 0; e < 8; ++e) pk[e] = lt[tt + e][dd];
    *(u16x8*)(vt + ((long)bh * 64 + dd) * CT + t0 + tt) = pk;
  }
}

// dw_w[512][31] f32 -> wT[31][512] f32
__global__ void dwt_k(const float* __restrict__ w, float* __restrict__ o)
{
  int i = blockIdx.x * 256 + threadIdx.x;
  if (i < 512 * 31) { int c = i / 31, k = i % 31; o[k * 512 + c] = w[i]; }
}

// ---------------------------------------------------------------------------
// LayerNorm over D=512, one block per row.
// ---------------------------------------------------------------------------
template<int OBF>
__global__ __launch_bounds__(256) void ln_k(
    const float* __restrict__ in, const float* __restrict__ g,
    const float* __restrict__ b, void* __restrict__ out)
{
  __shared__ float rs[4], rq[4];
  const long row = blockIdx.x;
  const int tid = threadIdx.x;
  float2 v = ((const float2*)(in + row * CD))[tid];
  float s = v.x + v.y, q = v.x * v.x + v.y * v.y;
#pragma unroll
  for (int o = 32; o; o >>= 1) { s += __shfl_xor(s, o); q += __shfl_xor(q, o); }
  if ((tid & 63) == 0) { rs[tid >> 6] = s; rq[tid >> 6] = q; }
  __syncthreads();
  s = rs[0] + rs[1] + rs[2] + rs[3];
  q = rq[0] + rq[1] + rq[2] + rq[3];
  float mean = s * (1.0f / CD);
  float var = q * (1.0f / CD) - mean * mean;
  float rstd = rsqrtf(var + 1e-5f);
  float2 gg = ((const float2*)g)[tid];
  float2 bb = ((const float2*)b)[tid];
  float ox = (v.x - mean) * rstd * gg.x + bb.x;
  float oy = (v.y - mean) * rstd * gg.y + bb.y;
  if (OBF) {
    unsigned pk = ((unsigned)f2bf(oy) << 16) | f2bf(ox);
    ((unsigned*)out)[row * 256 + tid] = pk;
  } else {
    ((float2*)out)[row * 256 + tid] = make_float2(ox, oy);
  }
}

__global__ void rope_table_k(float* __restrict__ cosT, float* __restrict__ sinT)
{
  int tid = blockIdx.x * 256 + threadIdx.x;     // T*32
  int t = tid >> 5, i = tid & 31;
  float freq = __expf(-(float)i * (9.210340371976184f / 32.0f));
  float ang = (float)t * freq;
  cosT[tid] = cosf(ang);
  sinT[tid] = sinf(ang);
}

// In-place RoPE on fused QKV (Q cols 0..511 scaled by 0.125*log2e, K 512..1023).
__global__ __launch_bounds__(256) void rope_k(
    unsigned* __restrict__ qkv,
    const float* __restrict__ cosT, const float* __restrict__ sinT)
{
  const float SC = 0.125f * 1.44269504089f;        // fold scale + log2(e) into Q
  long p = (long)blockIdx.x * 256 + threadIdx.x;   // B*T*256 pair slots
  int pr = (int)(p & 255);
  long row = p >> 8;
  int t = (int)(row & (CT - 1));
  int h = pr >> 5, i = pr & 31;
  float c = cosT[t * 32 + i], s = sinT[t * 32 + i];
  unsigned* base = qkv + row * 768 + h * 32 + i;
  unsigned v = base[0];
  float xe = bf2f((u16)v), xo = bf2f((u16)(v >> 16));
  base[0] = ((unsigned)f2bf((xe * s + xo * c) * SC) << 16) | f2bf((xe * c - xo * s) * SC);
  v = base[256];
  xe = bf2f((u16)v); xo = bf2f((u16)(v >> 16));
  base[256] = ((unsigned)f2bf(xe * s + xo * c) << 16) | f2bf(xe * c - xo * s);
}

// GLU
__global__ __launch_bounds__(256) void glu_k(
    const u16* __restrict__ t, u16* __restrict__ out)
{
  long idx = (long)blockIdx.x * 256 + threadIdx.x;  // BT*128
  long row = idx >> 7;
  int c4 = (int)(idx & 127) * 4;
  u16x4 a = *(const u16x4*)(t + row * 1024 + c4);
  u16x4 b = *(const u16x4*)(t + row * 1024 + 512 + c4);
  u16x4 o;
#pragma unroll
  for (int e = 0; e < 4; ++e) o[e] = f2bf(bf2f(a[e]) * sigm(bf2f(b[e])));
  *(u16x4*)(out + row * CD + c4) = o;
}

// Depthwise conv1d: bf16 in, f32 out. 8 t-outputs x 4 channels/thread.
__global__ __launch_bounds__(256) void dwconv_k(
    const u16* __restrict__ in, const float* __restrict__ wT,
    const float* __restrict__ wb, float* __restrict__ out)
{
  long idx = (long)blockIdx.x * 256 + threadIdx.x;  // B*(T/8)*(D/4)
  int c4 = (int)(idx & 127) * 4;
  int t0 = (int)((idx >> 7) & 255) * 8;
  int b = (int)(idx >> 15);
  const u16* base = in + (long)b * CT * CD;
  float4 bias = *(const float4*)(wb + c4);
  float4 acc[8];
#pragma unroll
  for (int t = 0; t < 8; ++t) acc[t] = bias;
#pragma unroll
  for (int j = 0; j < 38; ++j) {
    int tr = t0 + j - 15;
    float4 row = make_float4(0.f, 0.f, 0.f, 0.f);
    if (tr >= 0 && tr < CT) {
      u16x4 rv = *(const u16x4*)(base + (long)tr * CD + c4);
      row = make_float4(bf2f(rv[0]), bf2f(rv[1]), bf2f(rv[2]), bf2f(rv[3]));
    }
#pragma unroll
    for (int t = 0; t < 8; ++t) {
      int k = j - t;
      if (k >= 0 && k < CK) {
        float4 w4 = *(const float4*)(wT + k * CD + c4);
        acc[t].x += row.x * w4.x; acc[t].y += row.y * w4.y;
        acc[t].z += row.z * w4.z; acc[t].w += row.w * w4.w;
      }
    }
  }
#pragma unroll
  for (int t = 0; t < 8; ++t)
    *(float4*)(out + ((long)b * CT + t0 + t) * CD + c4) = acc[t];
}

__global__ __launch_bounds__(256) void bn_part_k(
    const float* __restrict__ in, float* __restrict__ psum, float* __restrict__ psq)
{
  const int blk = blockIdx.x;        // 64
  const int tid = threadIdx.x;
  const int c0 = tid, c1 = tid + 256;
  const int rows = CBT / 64;
  const float* base = in + (long)blk * rows * CD;
  float s0 = 0, q0 = 0, s1 = 0, q1 = 0;
  for (int r = 0; r < rows; ++r) {
    float v0 = base[(long)r * CD + c0]; s0 += v0; q0 += v0 * v0;
    float v1 = base[(long)r * CD + c1]; s1 += v1; q1 += v1 * v1;
  }
  psum[blk * CD + c0] = s0; psq[blk * CD + c0] = q0;
  psum[blk * CD + c1] = s1; psq[blk * CD + c1] = q1;
}

__global__ __launch_bounds__(256) void bn_fin_k(
    const float* __restrict__ psum, const float* __restrict__ psq,
    float* __restrict__ stat)
{
  int c = blockIdx.x * 256 + threadIdx.x;
  float s = 0, q = 0;
  for (int i = 0; i < 64; ++i) { s += psum[i * CD + c]; q += psq[i * CD + c]; }
  float mean = s * (1.0f / CBT);
  float var = q * (1.0f / CBT) - mean * mean;
  stat[c] = mean;
  stat[CD + c] = rsqrtf(var + 1e-5f);
}

__global__ __launch_bounds__(256) void bn_app_k(
    const float* __restrict__ h, const float* __restrict__ stat,
    const float* __restrict__ g, const float* __restrict__ b,
    u16* __restrict__ out)
{
  long idx = (long)blockIdx.x * 256 + threadIdx.x;
  int c = (int)(idx & 511);
  float v = (h[idx] - stat[c]) * stat[CD + c] * g[c] + b[c];
  v = v * sigm(v);
  out[idx] = f2bf(v);
}

// ---------------------------------------------------------------------------
// Host launcher
// ---------------------------------------------------------------------------
extern "C" void kernel_launch(void* const* d_in, const int* in_sizes, int n_in,
                              void* d_out, int out_size, void* d_ws, size_t ws_size,
                              hipStream_t stream)
{
  const float* x        = (const float*)d_in[0];
  const float* ff1_lng  = (const float*)d_in[1];
  const float* ff1_lnb  = (const float*)d_in[2];
  const float* ff1_w1   = (const float*)d_in[3];
  const float* ff1_b1   = (const float*)d_in[4];
  const float* ff1_w2   = (const float*)d_in[5];
  const float* ff1_b2   = (const float*)d_in[6];
  const float* attn_lng = (const float*)d_in[7];
  const float* attn_lnb = (const float*)d_in[8];
  const float* wq       = (const float*)d_in[9];
  const float* wk       = (const float*)d_in[10];
  const float* wv       = (const float*)d_in[11];
  const float* wo       = (const float*)d_in[12];
  const float* conv_lng = (const float*)d_in[13];
  const float* conv_lnb = (const float*)d_in[14];
  const float* pw1_w    = (const float*)d_in[15];
  const float* pw1_b    = (const float*)d_in[16];
  const float* dw_w     = (const float*)d_in[17];
  const float* dw_b     = (const float*)d_in[18];
  const float* bn_g     = (const float*)d_in[19];
  const float* bn_b     = (const float*)d_in[20];
  const float* pw2_w    = (const float*)d_in[21];
  const float* pw2_b    = (const float*)d_in[22];
  const float* ff2_lng  = (const float*)d_in[23];
  const float* ff2_lnb  = (const float*)d_in[24];
  const float* ff2_w1   = (const float*)d_in[25];
  const float* ff2_b1   = (const float*)d_in[26];
  const float* ff2_w2   = (const float*)d_in[27];
  const float* ff2_b2   = (const float*)d_in[28];
  const float* out_lng  = (const float*)d_in[29];
  const float* out_lnb  = (const float*)d_in[30];
  float* out = (float*)d_out;

  char* p = (char*)d_ws;
  auto alloc = [&](size_t bytes) { char* r = p; p += (bytes + 255) & ~(size_t)255; return r; };
  float*  bufX   = (float*)alloc((size_t)CBT * CD * 4);
  float*  bufC   = (float*)alloc((size_t)CBT * CD * 4);
  bf16_t* bufH   = (bf16_t*)alloc((size_t)CBT * CD * 2);
  bf16_t* bufQKV = (bf16_t*)alloc((size_t)CBT * 1536 * 2);
  bf16_t* bufO   = (bf16_t*)alloc((size_t)CBT * CD * 2);
  bf16_t* bufVT  = (bf16_t*)alloc((size_t)CBT * CD * 2);
  bf16_t* bufP   = (bf16_t*)alloc((size_t)CBT * CINNER * 2);
  bf16_t* w_ff1a = (bf16_t*)alloc((size_t)CD * CINNER * 2);
  bf16_t* w_ff1b = (bf16_t*)alloc((size_t)CD * CINNER * 2);
  bf16_t* w_qkv  = (bf16_t*)alloc((size_t)CD * 1536 * 2);
  bf16_t* w_o    = (bf16_t*)alloc((size_t)CD * CD * 2);
  bf16_t* w_pw1  = (bf16_t*)alloc((size_t)CD * 2 * CD * 2);
  bf16_t* w_pw2  = (bf16_t*)alloc((size_t)CD * CD * 2);
  bf16_t* w_ff2a = (bf16_t*)alloc((size_t)CD * CINNER * 2);
  bf16_t* w_ff2b = (bf16_t*)alloc((size_t)CD * CINNER * 2);
  float* dwT  = (float*)alloc((size_t)CK * CD * 4);
  float* cosT = (float*)alloc((size_t)CT * 32 * 4);
  float* sinT = (float*)alloc((size_t)CT * 32 * 4);
  float* psum = (float*)alloc((size_t)64 * CD * 4);
  float* psq  = (float*)alloc((size_t)64 * CD * 4);
  float* stat = (float*)alloc((size_t)2 * CD * 4);

  const dim3 blk(256);

  wtrans_k<<<dim3(CINNER / 64, CD / 64), blk, 0, stream>>>(ff1_w1, (u16*)w_ff1a, CD, CINNER);
  wtrans_k<<<dim3(CD / 64, CINNER / 64), blk, 0, stream>>>(ff1_w2, (u16*)w_ff1b, CINNER, CD);
  wtrans_k<<<dim3(CD / 64, CD / 64), blk, 0, stream>>>(wq, (u16*)w_qkv, CD, CD);
  wtrans_k<<<dim3(CD / 64, CD / 64), blk, 0, stream>>>(wk, (u16*)(w_qkv + (size_t)512 * CD), CD, CD);
  wtrans_k<<<dim3(CD / 64, CD / 64), blk, 0, stream>>>(wv, (u16*)(w_qkv + (size_t)1024 * CD), CD, CD);
  wtrans_k<<<dim3(CD / 64, CD / 64), blk, 0, stream>>>(wo, (u16*)w_o, CD, CD);
  wtrans_k<<<dim3(2 * CD / 64, CD / 64), blk, 0, stream>>>(pw1_w, (u16*)w_pw1, CD, 2 * CD);
  wtrans_k<<<dim3(CD / 64, CD / 64), blk, 0, stream>>>(pw2_w, (u16*)w_pw2, CD, CD);
  wtrans_k<<<dim3(CINNER / 64, CD / 64), blk, 0, stream>>>(ff2_w1, (u16*)w_ff2a, CD, CINNER);
  wtrans_k<<<dim3(CD / 64, CINNER / 64), blk, 0, stream>>>(ff2_w2, (u16*)w_ff2b, CINNER, CD);
  dwt_k<<<dim3(62), blk, 0, stream>>>(dw_w, dwT);
  rope_table_k<<<dim3(CT * 32 / 256), blk, 0, stream>>>(cosT, sinT);

  // ---- FF1 ----
  ln_k<1><<<dim3(CBT), blk, 0, stream>>>(x, ff1_lng, ff1_lnb, bufH);
  gemm_bf<128, 128, EPI_SILU_BF><<<dim3(16, 64, 1), blk, 0, stream>>>(
      bufH, w_ff1a, ff1_b1, nullptr, bufP, CD, CD, CINNER, CD, 1.0f, 0, 0, 0);
  gemm_bf<64, 128, EPI_RES><<<dim3(4, 128, 1), blk, 0, stream>>>(
      bufP, w_ff1b, ff1_b2, x, bufX, CINNER, CINNER, CD, CINNER, 0.5f, 0, 0, 0);

  // ---- Attention ----
  ln_k<1><<<dim3(CBT), blk, 0, stream>>>(bufX, attn_lng, attn_lnb, bufH);
  gemm_bf<128, 128, EPI_BF><<<dim3(12, 64, 1), blk, 0, stream>>>(
      bufH, w_qkv, nullptr, nullptr, bufQKV, CD, CD, 1536, CD, 1.0f, 0, 0, 0);
  rope_k<<<dim3(CB * CT), blk, 0, stream>>>((unsigned*)bufQKV, cosT, sinT);
  vtrans_k<<<dim3(CT / 64, CB * CH), blk, 0, stream>>>((const u16*)bufQKV, (u16*)bufVT);
  fattn_k<<<dim3(CT / 128, CB * CH), blk, 0, stream>>>(bufQKV, bufVT, bufO);
  gemm_bf<64, 128, EPI_RES><<<dim3(4, 128, 1), blk, 0, stream>>>(
      bufO, w_o, nullptr, bufX, bufX, CD, CD, CD, CD, 1.0f, 0, 0, 0);

  // ---- Conv module ----
  ln_k<1><<<dim3(CBT), blk, 0, stream>>>(bufX, conv_lng, conv_lnb, bufH);
  gemm_bf<128, 128, EPI_BF><<<dim3(8, 64, 1), blk, 0, stream>>>(
      bufH, w_pw1, pw1_b, nullptr, bufP, CD, CD, 2 * CD, CD, 1.0f, 0, 0, 0);
  glu_k<<<dim3(CBT * 128 / 256), blk, 0, stream>>>((const u16*)bufP, (u16*)bufH);
  dwconv_k<<<dim3(512), blk, 0, stream>>>((const u16*)bufH, dwT, dw_b, bufC);
  bn_part_k<<<dim3(64), blk, 0, stream>>>(bufC, psum, psq);
  bn_fin_k<<<dim3(2), blk, 0, stream>>>(psum, psq, stat);
  bn_app_k<<<dim3(CBT * CD / 256), blk, 0, stream>>>(bufC, stat, bn_g, bn_b, (u16*)bufH);
  gemm_bf<64, 128, EPI_RES><<<dim3(4, 128, 1), blk, 0, stream>>>(
      bufH, w_pw2, pw2_b, bufX, bufX, CD, CD, CD, CD, 1.0f, 0, 0, 0);

  // ---- FF2 ----
  ln_k<1><<<dim3(CBT), blk, 0, stream>>>(bufX, ff2_lng, ff2_lnb, bufH);
  gemm_bf<128, 128, EPI_SILU_BF><<<dim3(16, 64, 1), blk, 0, stream>>>(
      bufH, w_ff2a, ff2_b1, nullptr, bufP, CD, CD, CINNER, CD, 1.0f, 0, 0, 0);
  gemm_bf<64, 128, EPI_RES><<<dim3(4, 128, 1), blk, 0, stream>>>(
      bufP, w_ff2b, ff2_b2, bufX, bufX, CINNER, CINNER, CD, CINNER, 0.5f, 0, 0, 0);

  // ---- Output LN ----
  ln_k<0><<<dim3(CBT), blk, 0, stream>>>(bufX, out_lng, out_lnb, out);

  (void)in_sizes; (void)n_in; (void)out_size; (void)ws_size;
}

// Round 5
// 435.657 us; speedup vs baseline: 3.7520x; 1.1021x over previous
//
#include <hip/hip_runtime.h>

// ---------------------------------------------------------------------------
// STTConformerBlock: B=4 T=2048 D=512 H=8 DH=64 INNER=2048 K=31, f32 I/O.
// bf16 MFMA GEMMs (B pre-transposed [N][K]), global_load_lds staging with
// XOR bank swizzle. Flash attention: swapped-QK^T 32x32 MFMA, LDS-staged
// coalesced K/V (double-buffered), in-register softmax, exp2, defer-max.
// ---------------------------------------------------------------------------

typedef float  f32x4   __attribute__((ext_vector_type(4)));
typedef float  f32x16  __attribute__((ext_vector_type(16)));
typedef __bf16 bf16_t;
typedef __bf16 bf16x8  __attribute__((ext_vector_type(8)));
typedef unsigned short u16;
typedef unsigned short u16x4 __attribute__((ext_vector_type(4)));
typedef unsigned short u16x8 __attribute__((ext_vector_type(8)));
typedef unsigned int   u32x4 __attribute__((ext_vector_type(4)));

#define DEVI __device__ __forceinline__

static constexpr int CB = 4, CT = 2048, CD = 512, CH = 8, CDH = 64, CINNER = 2048, CK = 31;
static constexpr int CBT = CB * CT;
static constexpr long TDE = (long)CT * CD;

DEVI u16 f2bf(float f) {
  unsigned u = __builtin_bit_cast(unsigned, f);
  u += 0x7FFFu + ((u >> 16) & 1u);
  return (u16)(u >> 16);
}
DEVI float bf2f(u16 h) { return __builtin_bit_cast(float, (unsigned)h << 16); }
DEVI float sigm(float x) { return 1.0f / (1.0f + __expf(-x)); }

DEVI unsigned cvtpk(float lo, float hi) {
  unsigned r;
  asm("v_cvt_pk_bf16_f32 %0, %1, %2" : "=v"(r) : "v"(lo), "v"(hi));
  return r;
}

DEVI void gload16(const bf16_t* g, bf16_t* l) {
  __builtin_amdgcn_global_load_lds(
      (const __attribute__((address_space(1))) unsigned int*)g,
      (__attribute__((address_space(3))) unsigned int*)l, 16, 0, 0);
}

enum { EPI_BF = 0, EPI_SILU_BF = 1, EPI_RES = 2 };

// ---------------------------------------------------------------------------
// bf16 GEMM: C[M,N] = epi( A[M,K] @ B[N,K]^T * scale + bias )
// ---------------------------------------------------------------------------
template<int BM, int BN, int EPI>
__global__ __launch_bounds__(256) void gemm_bf(
    const bf16_t* __restrict__ A, const bf16_t* __restrict__ B,
    const float* __restrict__ bias, const float* __restrict__ res,
    void* __restrict__ Cv,
    int lda, int ldb, int ldc, int Kd, float scale,
    long sA, long sB, long sC)
{
  __shared__ __align__(16) bf16_t As[BM * 64];
  __shared__ __align__(16) bf16_t Bs[BN * 64];

  const long z = blockIdx.z;
  A += z * sA;
  B += z * sB;
  const long oC = z * sC;

  const int m0 = blockIdx.y * BM, n0 = blockIdx.x * BN;
  const int tid = threadIdx.x;
  const int wid = tid >> 6, lane = tid & 63;
  const int lrow = lane & 15, lk = lane >> 4;
  constexpr int FM = BM / 32, FN = BN / 32;
  const int wm = (wid >> 1) * (BM / 2), wn = (wid & 1) * (BN / 2);
  const int r8 = tid >> 3;
  const int cs = (((tid & 7) ^ (r8 & 7)) << 3);
  const int fsw = lrow & 7;

  f32x4 acc[FM][FN] = {};

  for (int k0 = 0; k0 < Kd; k0 += 64) {
    const bf16_t* ga = A + (long)(m0 + r8) * lda + (k0 + cs);
    const bf16_t* gb = B + (long)(n0 + r8) * ldb + (k0 + cs);
#pragma unroll
    for (int it = 0; it < BM / 32; ++it)
      gload16(ga + (long)it * 32 * lda, &As[tid * 8 + it * 2048]);
#pragma unroll
    for (int it = 0; it < BN / 32; ++it)
      gload16(gb + (long)it * 32 * ldb, &Bs[tid * 8 + it * 2048]);
    __syncthreads();

    bf16x8 av[2][FM], bv[2][FN];
#pragma unroll
    for (int kk = 0; kk < 2; ++kk) {
#pragma unroll
      for (int i = 0; i < FM; ++i)
        av[kk][i] = *(const bf16x8*)&As[(wm + i * 16 + lrow) * 64 + ((((kk << 2) + lk) ^ fsw) << 3)];
#pragma unroll
      for (int j = 0; j < FN; ++j)
        bv[kk][j] = *(const bf16x8*)&Bs[(wn + j * 16 + lrow) * 64 + ((((kk << 2) + lk) ^ fsw) << 3)];
    }
#pragma unroll
    for (int kk = 0; kk < 2; ++kk)
#pragma unroll
      for (int i = 0; i < FM; ++i)
#pragma unroll
        for (int j = 0; j < FN; ++j)
          acc[i][j] = __builtin_amdgcn_mfma_f32_16x16x32_bf16(av[kk][i], bv[kk][j], acc[i][j], 0, 0, 0);
    __syncthreads();
  }

#pragma unroll
  for (int j = 0; j < FN; ++j) {
    int col = n0 + wn + j * 16 + lrow;
    float bb = bias ? bias[col] : 0.0f;
#pragma unroll
    for (int i = 0; i < FM; ++i) {
#pragma unroll
      for (int r = 0; r < 4; ++r) {
        int row = m0 + wm + i * 16 + lk * 4 + r;
        long idx = oC + (long)row * ldc + col;
        float v = (acc[i][j][r] + bb) * scale;
        if constexpr (EPI == EPI_SILU_BF) v *= sigm(v);
        if constexpr (EPI == EPI_RES) {
          ((float*)Cv)[idx] = res[idx] + v;
        } else {
          ((bf16_t*)Cv)[idx] = (bf16_t)v;
        }
      }
    }
  }
}

// ---------------------------------------------------------------------------
// Flash attention, swapped-QK^T 32x32 MFMA. Block = 128 q-rows of one (b,h),
// 4 waves, each wave owns 32 q-rows. K/V staged cooperatively into LDS
// (coalesced gload_lds, XOR-swizzled both-sides, double-buffered 64-kv tiles).
// Softmax fully in-register (exp2 domain, defer-max THR=8), P packed via
// v_cvt_pk_bf16_f32 + v_permlane32_swap_b32.
// LDS 32 KB (u16 units): [K0 0][V0 4096][K1 8192][V1 12288]; Q staged once
// into 8192..16383 before the loop.
// ---------------------------------------------------------------------------
__global__ __launch_bounds__(256) void fattn_k(
    const bf16_t* __restrict__ QK,   // [B*T][1536], Q at 0, K at 512
    const bf16_t* __restrict__ VT,   // [B*H][64][2048]
    bf16_t* __restrict__ O)          // [B*T][512]
{
  __shared__ __align__(16) bf16_t S[16384];      // 32 KB

  const int tid = threadIdx.x;
  const int w = tid >> 6, lane = tid & 63;
  const int l31 = lane & 31, hi = lane >> 5;
  const int q0 = blockIdx.x * 128;
  const int bh = blockIdx.y, b = bh >> 3, h = bh & 7;

  const int r8 = tid >> 3;                          // stage row 0..31
  const int csw = ((tid & 7) ^ (r8 & 7)) << 3;      // swizzled src col (elems)
  const int fswl = l31 & 7;                         // frag-read swizzle

  const bf16_t* Qg = QK + ((long)b * CT + q0) * 1536 + h * 64;
  const bf16_t* Kg = QK + (long)b * CT * 1536 + 512 + h * 64;
  const bf16_t* Vg = VT + (long)bh * 64 * 2048;

  // ---- prologue: stage Q (->8192, 128x64), K tile0 (->0), V tile0 (->4096)
#pragma unroll
  for (int it = 0; it < 4; ++it)
    gload16(Qg + (long)(r8 + it * 32) * 1536 + csw, &S[8192 + tid * 8 + it * 2048]);
#pragma unroll
  for (int it = 0; it < 2; ++it)
    gload16(Kg + (long)(r8 + it * 32) * 1536 + csw, &S[tid * 8 + it * 2048]);
#pragma unroll
  for (int it = 0; it < 2; ++it)
    gload16(Vg + (long)(r8 + it * 32) * 2048 + csw, &S[4096 + tid * 8 + it * 2048]);
  __syncthreads();

  bf16x8 qb[4];
#pragma unroll
  for (int m = 0; m < 4; ++m)
    qb[m] = *(const bf16x8*)&S[8192 + (w * 32 + l31) * 64 + (((m * 2 + hi) ^ fswl) << 3)];
  __syncthreads();

  f32x16 o0 = {}, o1 = {};
  float mrun = -3.0e38f, lrun = 0.0f;
  int cur = 0;

  for (int kv0 = 0; kv0 < CT; kv0 += 64) {
    // ---- stage next tile into buf cur^1 (overlaps with compute below) ----
    const int nxt = kv0 + 64;
    if (nxt < CT) {
      const int c2 = (cur ^ 1) * 8192;
#pragma unroll
      for (int it = 0; it < 2; ++it)
        gload16(Kg + (long)(nxt + r8 + it * 32) * 1536 + csw, &S[c2 + tid * 8 + it * 2048]);
#pragma unroll
      for (int it = 0; it < 2; ++it)
        gload16(Vg + (long)(r8 + it * 32) * 2048 + nxt + csw, &S[c2 + 4096 + tid * 8 + it * 2048]);
    }
    const bf16_t* Kb = &S[cur * 8192];
    const bf16_t* Vb = &S[cur * 8192 + 4096];

    // ---- S^T = K_tile @ Q : lane q = l31 ----
    bf16x8 ka[2][4];
#pragma unroll
    for (int j = 0; j < 2; ++j)
#pragma unroll
      for (int m = 0; m < 4; ++m)
        ka[j][m] = *(const bf16x8*)&Kb[(j * 32 + l31) * 64 + (((m * 2 + hi) ^ fswl) << 3)];

    f32x16 s0 = {}, s1 = {};
    __builtin_amdgcn_s_setprio(1);
#pragma unroll
    for (int m = 0; m < 4; ++m) {
      s0 = __builtin_amdgcn_mfma_f32_32x32x16_bf16(ka[0][m], qb[m], s0, 0, 0, 0);
      s1 = __builtin_amdgcn_mfma_f32_32x32x16_bf16(ka[1][m], qb[m], s1, 0, 0, 0);
    }
    __builtin_amdgcn_s_setprio(0);

    // ---- online softmax (per-lane q-row, cross-half shuffle only) ----
    float pm = fmaxf(s0[0], s1[0]);
#pragma unroll
    for (int r = 1; r < 16; ++r) pm = fmaxf(pm, fmaxf(s0[r], s1[r]));
    pm = fmaxf(pm, __shfl_xor(pm, 32));

    if (!__all(pm <= mrun + 8.0f)) {
      float mn = fmaxf(mrun, pm);
      float al = exp2f(mrun - mn);
      mrun = mn;
      lrun *= al;
#pragma unroll
      for (int r = 0; r < 16; ++r) { o0[r] *= al; o1[r] *= al; }
    }

    float ps = 0.0f;
#pragma unroll
    for (int r = 0; r < 16; ++r) { s0[r] = exp2f(s0[r] - mrun); ps += s0[r]; }
#pragma unroll
    for (int r = 0; r < 16; ++r) { s1[r] = exp2f(s1[r] - mrun); ps += s1[r]; }
    ps += __shfl_xor(ps, 32);
    lrun += ps;

    // ---- pack P^T -> B-frags: 16 cvt_pk + 8 permlane32_swap ----
    bf16x8 pw[4];
#pragma unroll
    for (int jk = 0; jk < 4; ++jk) {
      float e0, e1, e2, e3, e4, e5, e6, e7;
      if (jk == 0) { e0=s0[0];e1=s0[1];e2=s0[2];e3=s0[3];e4=s0[4];e5=s0[5];e6=s0[6];e7=s0[7]; }
      else if (jk == 1) { e0=s0[8];e1=s0[9];e2=s0[10];e3=s0[11];e4=s0[12];e5=s0[13];e6=s0[14];e7=s0[15]; }
      else if (jk == 2) { e0=s1[0];e1=s1[1];e2=s1[2];e3=s1[3];e4=s1[4];e5=s1[5];e6=s1[6];e7=s1[7]; }
      else { e0=s1[8];e1=s1[9];e2=s1[10];e3=s1[11];e4=s1[12];e5=s1[13];e6=s1[14];e7=s1[15]; }
      unsigned a0 = cvtpk(e0, e1), a1 = cvtpk(e2, e3);
      unsigned b0 = cvtpk(e4, e5), b1 = cvtpk(e6, e7);
      asm("v_permlane32_swap_b32 %0, %1" : "+v"(a0), "+v"(b0));
      asm("v_permlane32_swap_b32 %0, %1" : "+v"(a1), "+v"(b1));
      u32x4 t; t[0] = a0; t[1] = a1; t[2] = b0; t[3] = b1;
      pw[jk] = __builtin_bit_cast(bf16x8, t);
    }

    // ---- O^T += V_tile^T @ P^T : lane d-row = l31 (+32 for o1) ----
    bf16x8 va[2][4];
#pragma unroll
    for (int n = 0; n < 2; ++n)
#pragma unroll
      for (int jk = 0; jk < 4; ++jk)
        va[n][jk] = *(const bf16x8*)&Vb[(n * 32 + l31) * 64 + (((jk * 2 + hi) ^ fswl) << 3)];

    __builtin_amdgcn_s_setprio(1);
#pragma unroll
    for (int jk = 0; jk < 4; ++jk) {
      o0 = __builtin_amdgcn_mfma_f32_32x32x16_bf16(va[0][jk], pw[jk], o0, 0, 0, 0);
      o1 = __builtin_amdgcn_mfma_f32_32x32x16_bf16(va[1][jk], pw[jk], o1, 0, 0, 0);
    }
    __builtin_amdgcn_s_setprio(0);

    __syncthreads();   // drains stage of next tile; protects buffer swap
    cur ^= 1;
  }

  // ---- epilogue: O[q][d] = O^T/l ----
  float rl = 1.0f / lrun;
  bf16_t* Op = O + ((long)b * CT + q0 + w * 32 + l31) * CD + h * 64;
#pragma unroll
  for (int n = 0; n < 2; ++n) {
#pragma unroll
    for (int m = 0; m < 4; ++m) {
      u16x4 pk4;
#pragma unroll
      for (int e = 0; e < 4; ++e)
        pk4[e] = f2bf((n ? o1[m * 4 + e] : o0[m * 4 + e]) * rl);
      *(u16x4*)(Op + n * 32 + m * 8 + hi * 4) = pk4;
    }
  }
}

// ---------------------------------------------------------------------------
// Weight convert+transpose: w[K][N] f32 -> o[N][K] bf16. 64x64 tiles.
// ---------------------------------------------------------------------------
__global__ __launch_bounds__(256) void wtrans_k(
    const float* __restrict__ w, u16* __restrict__ o, int Kd, int N)
{
  __shared__ u16 lt[64][72];
  const int k0 = blockIdx.y * 64, n0 = blockIdx.x * 64;
  const int tid = threadIdx.x;
#pragma unroll
  for (int it = 0; it < 4; ++it) {
    int kk = (tid >> 4) + it * 16, nn = (tid & 15) * 4;
    float4 f = *(const float4*)(w + (long)(k0 + kk) * N + n0 + nn);
    lt[kk][nn + 0] = f2bf(f.x); lt[kk][nn + 1] = f2bf(f.y);
    lt[kk][nn + 2] = f2bf(f.z); lt[kk][nn + 3] = f2bf(f.w);
  }
  __syncthreads();
#pragma unroll
  for (int it = 0; it < 2; ++it) {
    int nn = (tid >> 3) + it * 32, kk = (tid & 7) * 8;
    u16x8 pk;
#pragma unroll
    for (int e = 0; e < 8; ++e) pk[e] = lt[kk + e][nn];
    *(u16x8*)(o + (long)(n0 + nn) * Kd + k0 + kk) = pk;
  }
}

// V columns of bufQKV -> VT[bh][d][t]
__global__ __launch_bounds__(256) void vtrans_k(
    const u16* __restrict__ v, u16* __restrict__ vt)
{
  __shared__ u16 lt[64][72];
  const int bh = blockIdx.y, b = bh >> 3, h = bh & 7;
  const int t0 = blockIdx.x * 64;
  const int tid = threadIdx.x;
#pragma unroll
  for (int it = 0; it < 2; ++it) {
    int tt = (tid >> 3) + it * 32, dd = (tid & 7) * 8;
    u16x8 vv = *(const u16x8*)(v + ((long)b * CT + t0 + tt) * 1536 + 1024 + h * 64 + dd);
#pragma unroll
    for (int e = 0; e < 8; ++e) lt[tt][dd + e] = vv[e];
  }
  __syncthreads();
#pragma unroll
  for (int it = 0; it < 2; ++it) {
    int dd = (tid >> 3) + it * 32, tt = (tid & 7) * 8;
    u16x8 pk;
#pragma unroll
    for (int e = 0; e < 8; ++e) pk[e] = lt[tt + e][dd];
    *(u16x8*)(vt + ((long)bh * 64 + dd) * CT + t0 + tt) = pk;
  }
}

// dw_w[512][31] f32 -> wT[31][512] f32
__global__ void dwt_k(const float* __restrict__ w, float* __restrict__ o)
{
  int i = blockIdx.x * 256 + threadIdx.x;
  if (i < 512 * 31) { int c = i / 31, k = i % 31; o[k * 512 + c] = w[i]; }
}

// ---------------------------------------------------------------------------
// LayerNorm over D=512, one block per row.
// ---------------------------------------------------------------------------
template<int OBF>
__global__ __launch_bounds__(256) void ln_k(
    const float* __restrict__ in, const float* __restrict__ g,
    const float* __restrict__ b, void* __restrict__ out)
{
  __shared__ float rs[4], rq[4];
  const long row = blockIdx.x;
  const int tid = threadIdx.x;
  float2 v = ((const float2*)(in + row * CD))[tid];
  float s = v.x + v.y, q = v.x * v.x + v.y * v.y;
#pragma unroll
  for (int o = 32; o; o >>= 1) { s += __shfl_xor(s, o); q += __shfl_xor(q, o); }
  if ((tid & 63) == 0) { rs[tid >> 6] = s; rq[tid >> 6] = q; }
  __syncthreads();
  s = rs[0] + rs[1] + rs[2] + rs[3];
  q = rq[0] + rq[1] + rq[2] + rq[3];
  float mean = s * (1.0f / CD);
  float var = q * (1.0f / CD) - mean * mean;
  float rstd = rsqrtf(var + 1e-5f);
  float2 gg = ((const float2*)g)[tid];
  float2 bb = ((const float2*)b)[tid];
  float ox = (v.x - mean) * rstd * gg.x + bb.x;
  float oy = (v.y - mean) * rstd * gg.y + bb.y;
  if (OBF) {
    unsigned pk = ((unsigned)f2bf(oy) << 16) | f2bf(ox);
    ((unsigned*)out)[row * 256 + tid] = pk;
  } else {
    ((float2*)out)[row * 256 + tid] = make_float2(ox, oy);
  }
}

__global__ void rope_table_k(float* __restrict__ cosT, float* __restrict__ sinT)
{
  int tid = blockIdx.x * 256 + threadIdx.x;     // T*32
  int t = tid >> 5, i = tid & 31;
  float freq = __expf(-(float)i * (9.210340371976184f / 32.0f));
  float ang = (float)t * freq;
  cosT[tid] = cosf(ang);
  sinT[tid] = sinf(ang);
}

// In-place RoPE on fused QKV (Q cols 0..511 scaled by 0.125*log2e, K 512..1023).
__global__ __launch_bounds__(256) void rope_k(
    unsigned* __restrict__ qkv,
    const float* __restrict__ cosT, const float* __restrict__ sinT)
{
  const float SC = 0.125f * 1.44269504089f;
  long p = (long)blockIdx.x * 256 + threadIdx.x;   // B*T*256 pair slots
  int pr = (int)(p & 255);
  long row = p >> 8;
  int t = (int)(row & (CT - 1));
  int h = pr >> 5, i = pr & 31;
  float c = cosT[t * 32 + i], s = sinT[t * 32 + i];
  unsigned* base = qkv + row * 768 + h * 32 + i;
  unsigned v = base[0];
  float xe = bf2f((u16)v), xo = bf2f((u16)(v >> 16));
  base[0] = ((unsigned)f2bf((xe * s + xo * c) * SC) << 16) | f2bf((xe * c - xo * s) * SC);
  v = base[256];
  xe = bf2f((u16)v); xo = bf2f((u16)(v >> 16));
  base[256] = ((unsigned)f2bf(xe * s + xo * c) << 16) | f2bf(xe * c - xo * s);
}

// GLU
__global__ __launch_bounds__(256) void glu_k(
    const u16* __restrict__ t, u16* __restrict__ out)
{
  long idx = (long)blockIdx.x * 256 + threadIdx.x;  // BT*128
  long row = idx >> 7;
  int c4 = (int)(idx & 127) * 4;
  u16x4 a = *(const u16x4*)(t + row * 1024 + c4);
  u16x4 b = *(const u16x4*)(t + row * 1024 + 512 + c4);
  u16x4 o;
#pragma unroll
  for (int e = 0; e < 4; ++e) o[e] = f2bf(bf2f(a[e]) * sigm(bf2f(b[e])));
  *(u16x4*)(out + row * CD + c4) = o;
}

// Depthwise conv1d: bf16 in, bf16 out. 8 t-outputs x 4 channels/thread.
__global__ __launch_bounds__(256) void dwconv_k(
    const u16* __restrict__ in, const float* __restrict__ wT,
    const float* __restrict__ wb, u16* __restrict__ out)
{
  long idx = (long)blockIdx.x * 256 + threadIdx.x;  // B*(T/8)*(D/4)
  int c4 = (int)(idx & 127) * 4;
  int t0 = (int)((idx >> 7) & 255) * 8;
  int b = (int)(idx >> 15);
  const u16* base = in + (long)b * CT * CD;
  float4 bias = *(const float4*)(wb + c4);
  float4 acc[8];
#pragma unroll
  for (int t = 0; t < 8; ++t) acc[t] = bias;
#pragma unroll
  for (int j = 0; j < 38; ++j) {
    int tr = t0 + j - 15;
    float4 row = make_float4(0.f, 0.f, 0.f, 0.f);
    if (tr >= 0 && tr < CT) {
      u16x4 rv = *(const u16x4*)(base + (long)tr * CD + c4);
      row = make_float4(bf2f(rv[0]), bf2f(rv[1]), bf2f(rv[2]), bf2f(rv[3]));
    }
#pragma unroll
    for (int t = 0; t < 8; ++t) {
      int k = j - t;
      if (k >= 0 && k < CK) {
        float4 w4 = *(const float4*)(wT + k * CD + c4);
        acc[t].x += row.x * w4.x; acc[t].y += row.y * w4.y;
        acc[t].z += row.z * w4.z; acc[t].w += row.w * w4.w;
      }
    }
  }
#pragma unroll
  for (int t = 0; t < 8; ++t) {
    u16x4 pk;
    pk[0] = f2bf(acc[t].x); pk[1] = f2bf(acc[t].y);
    pk[2] = f2bf(acc[t].z); pk[3] = f2bf(acc[t].w);
    *(u16x4*)(out + ((long)b * CT + t0 + t) * CD + c4) = pk;
  }
}

__global__ __launch_bounds__(256) void bn_part_k(
    const u16* __restrict__ in, float* __restrict__ psum, float* __restrict__ psq)
{
  const int blk = blockIdx.x;        // 64
  const int tid = threadIdx.x;
  const int c0 = tid, c1 = tid + 256;
  const int rows = CBT / 64;
  const u16* base = in + (long)blk * rows * CD;
  float s0 = 0, q0 = 0, s1 = 0, q1 = 0;
  for (int r = 0; r < rows; ++r) {
    float v0 = bf2f(base[(long)r * CD + c0]); s0 += v0; q0 += v0 * v0;
    float v1 = bf2f(base[(long)r * CD + c1]); s1 += v1; q1 += v1 * v1;
  }
  psum[blk * CD + c0] = s0; psq[blk * CD + c0] = q0;
  psum[blk * CD + c1] = s1; psq[blk * CD + c1] = q1;
}

__global__ __launch_bounds__(256) void bn_fin_k(
    const float* __restrict__ psum, const float* __restrict__ psq,
    float* __restrict__ stat)
{
  int c = blockIdx.x * 256 + threadIdx.x;
  float s = 0, q = 0;
  for (int i = 0; i < 64; ++i) { s += psum[i * CD + c]; q += psq[i * CD + c]; }
  float mean = s * (1.0f / CBT);
  float var = q * (1.0f / CBT) - mean * mean;
  stat[c] = mean;
  stat[CD + c] = rsqrtf(var + 1e-5f);
}

__global__ __launch_bounds__(256) void bn_app_k(
    const u16* __restrict__ h, const float* __restrict__ stat,
    const float* __restrict__ g, const float* __restrict__ b,
    u16* __restrict__ out)
{
  long idx = (long)blockIdx.x * 256 + threadIdx.x;
  int c = (int)(idx & 511);
  float v = (bf2f(h[idx]) - stat[c]) * stat[CD + c] * g[c] + b[c];
  v = v * sigm(v);
  out[idx] = f2bf(v);
}

// ---------------------------------------------------------------------------
// Host launcher
// ---------------------------------------------------------------------------
extern "C" void kernel_launch(void* const* d_in, const int* in_sizes, int n_in,
                              void* d_out, int out_size, void* d_ws, size_t ws_size,
                              hipStream_t stream)
{
  const float* x        = (const float*)d_in[0];
  const float* ff1_lng  = (const float*)d_in[1];
  const float* ff1_lnb  = (const float*)d_in[2];
  const float* ff1_w1   = (const float*)d_in[3];
  const float* ff1_b1   = (const float*)d_in[4];
  const float* ff1_w2   = (const float*)d_in[5];
  const float* ff1_b2   = (const float*)d_in[6];
  const float* attn_lng = (const float*)d_in[7];
  const float* attn_lnb = (const float*)d_in[8];
  const float* wq       = (const float*)d_in[9];
  const float* wk       = (const float*)d_in[10];
  const float* wv       = (const float*)d_in[11];
  const float* wo       = (const float*)d_in[12];
  const float* conv_lng = (const float*)d_in[13];
  const float* conv_lnb = (const float*)d_in[14];
  const float* pw1_w    = (const float*)d_in[15];
  const float* pw1_b    = (const float*)d_in[16];
  const float* dw_w     = (const float*)d_in[17];
  const float* dw_b     = (const float*)d_in[18];
  const float* bn_g     = (const float*)d_in[19];
  const float* bn_b     = (const float*)d_in[20];
  const float* pw2_w    = (const float*)d_in[21];
  const float* pw2_b    = (const float*)d_in[22];
  const float* ff2_lng  = (const float*)d_in[23];
  const float* ff2_lnb  = (const float*)d_in[24];
  const float* ff2_w1   = (const float*)d_in[25];
  const float* ff2_b1   = (const float*)d_in[26];
  const float* ff2_w2   = (const float*)d_in[27];
  const float* ff2_b2   = (const float*)d_in[28];
  const float* out_lng  = (const float*)d_in[29];
  const float* out_lnb  = (const float*)d_in[30];
  float* out = (float*)d_out;

  char* p = (char*)d_ws;
  auto alloc = [&](size_t bytes) { char* r = p; p += (bytes + 255) & ~(size_t)255; return r; };
  float*  bufX   = (float*)alloc((size_t)CBT * CD * 4);
  bf16_t* bufH   = (bf16_t*)alloc((size_t)CBT * CD * 2);
  bf16_t* bufQKV = (bf16_t*)alloc((size_t)CBT * 1536 * 2);
  bf16_t* bufO   = (bf16_t*)alloc((size_t)CBT * CD * 2);
  bf16_t* bufVT  = (bf16_t*)alloc((size_t)CBT * CD * 2);
  bf16_t* bufP   = (bf16_t*)alloc((size_t)CBT * CINNER * 2);
  bf16_t* w_ff1a = (bf16_t*)alloc((size_t)CD * CINNER * 2);
  bf16_t* w_ff1b = (bf16_t*)alloc((size_t)CD * CINNER * 2);
  bf16_t* w_qkv  = (bf16_t*)alloc((size_t)CD * 1536 * 2);
  bf16_t* w_o    = (bf16_t*)alloc((size_t)CD * CD * 2);
  bf16_t* w_pw1  = (bf16_t*)alloc((size_t)CD * 2 * CD * 2);
  bf16_t* w_pw2  = (bf16_t*)alloc((size_t)CD * CD * 2);
  bf16_t* w_ff2a = (bf16_t*)alloc((size_t)CD * CINNER * 2);
  bf16_t* w_ff2b = (bf16_t*)alloc((size_t)CD * CINNER * 2);
  float* dwT  = (float*)alloc((size_t)CK * CD * 4);
  float* cosT = (float*)alloc((size_t)CT * 32 * 4);
  float* sinT = (float*)alloc((size_t)CT * 32 * 4);
  float* psum = (float*)alloc((size_t)64 * CD * 4);
  float* psq  = (float*)alloc((size_t)64 * CD * 4);
  float* stat = (float*)alloc((size_t)2 * CD * 4);

  const dim3 blk(256);

  wtrans_k<<<dim3(CINNER / 64, CD / 64), blk, 0, stream>>>(ff1_w1, (u16*)w_ff1a, CD, CINNER);
  wtrans_k<<<dim3(CD / 64, CINNER / 64), blk, 0, stream>>>(ff1_w2, (u16*)w_ff1b, CINNER, CD);
  wtrans_k<<<dim3(CD / 64, CD / 64), blk, 0, stream>>>(wq, (u16*)w_qkv, CD, CD);
  wtrans_k<<<dim3(CD / 64, CD / 64), blk, 0, stream>>>(wk, (u16*)(w_qkv + (size_t)512 * CD), CD, CD);
  wtrans_k<<<dim3(CD / 64, CD / 64), blk, 0, stream>>>(wv, (u16*)(w_qkv + (size_t)1024 * CD), CD, CD);
  wtrans_k<<<dim3(CD / 64, CD / 64), blk, 0, stream>>>(wo, (u16*)w_o, CD, CD);
  wtrans_k<<<dim3(2 * CD / 64, CD / 64), blk, 0, stream>>>(pw1_w, (u16*)w_pw1, CD, 2 * CD);
  wtrans_k<<<dim3(CD / 64, CD / 64), blk, 0, stream>>>(pw2_w, (u16*)w_pw2, CD, CD);
  wtrans_k<<<dim3(CINNER / 64, CD / 64), blk, 0, stream>>>(ff2_w1, (u16*)w_ff2a, CD, CINNER);
  wtrans_k<<<dim3(CD / 64, CINNER / 64), blk, 0, stream>>>(ff2_w2, (u16*)w_ff2b, CINNER, CD);
  dwt_k<<<dim3(62), blk, 0, stream>>>(dw_w, dwT);
  rope_table_k<<<dim3(CT * 32 / 256), blk, 0, stream>>>(cosT, sinT);

  // ---- FF1 ----
  ln_k<1><<<dim3(CBT), blk, 0, stream>>>(x, ff1_lng, ff1_lnb, bufH);
  gemm_bf<128, 128, EPI_SILU_BF><<<dim3(16, 64, 1), blk, 0, stream>>>(
      bufH, w_ff1a, ff1_b1, nullptr, bufP, CD, CD, CINNER, CD, 1.0f, 0, 0, 0);
  gemm_bf<64, 128, EPI_RES><<<dim3(4, 128, 1), blk, 0, stream>>>(
      bufP, w_ff1b, ff1_b2, x, bufX, CINNER, CINNER, CD, CINNER, 0.5f, 0, 0, 0);

  // ---- Attention ----
  ln_k<1><<<dim3(CBT), blk, 0, stream>>>(bufX, attn_lng, attn_lnb, bufH);
  gemm_bf<128, 128, EPI_BF><<<dim3(12, 64, 1), blk, 0, stream>>>(
      bufH, w_qkv, nullptr, nullptr, bufQKV, CD, CD, 1536, CD, 1.0f, 0, 0, 0);
  rope_k<<<dim3(CB * CT), blk, 0, stream>>>((unsigned*)bufQKV, cosT, sinT);
  vtrans_k<<<dim3(CT / 64, CB * CH), blk, 0, stream>>>((const u16*)bufQKV, (u16*)bufVT);
  fattn_k<<<dim3(CT / 128, CB * CH), blk, 0, stream>>>(bufQKV, bufVT, bufO);
  gemm_bf<64, 128, EPI_RES><<<dim3(4, 128, 1), blk, 0, stream>>>(
      bufO, w_o, nullptr, bufX, bufX, CD, CD, CD, CD, 1.0f, 0, 0, 0);

  // ---- Conv module ----
  ln_k<1><<<dim3(CBT), blk, 0, stream>>>(bufX, conv_lng, conv_lnb, bufH);
  gemm_bf<128, 128, EPI_BF><<<dim3(8, 64, 1), blk, 0, stream>>>(
      bufH, w_pw1, pw1_b, nullptr, bufP, CD, CD, 2 * CD, CD, 1.0f, 0, 0, 0);
  glu_k<<<dim3(CBT * 128 / 256), blk, 0, stream>>>((const u16*)bufP, (u16*)bufH);
  dwconv_k<<<dim3(512), blk, 0, stream>>>((const u16*)bufH, dwT, dw_b, (u16*)bufO);
  bn_part_k<<<dim3(64), blk, 0, stream>>>((const u16*)bufO, psum, psq);
  bn_fin_k<<<dim3(2), blk, 0, stream>>>(psum, psq, stat);
  bn_app_k<<<dim3(CBT * CD / 256), blk, 0, stream>>>((const u16*)bufO, stat, bn_g, bn_b, (u16*)bufH);
  gemm_bf<64, 128, EPI_RES><<<dim3(4, 128, 1), blk, 0, stream>>>(
      bufH, w_pw2, pw2_b, bufX, bufX, CD, CD, CD, CD, 1.0f, 0, 0, 0);

  // ---- FF2 ----
  ln_k<1><<<dim3(CBT), blk, 0, stream>>>(bufX, ff2_lng, ff2_lnb, bufH);
  gemm_bf<128, 128, EPI_SILU_BF><<<dim3(16, 64, 1), blk, 0, stream>>>(
      bufH, w_ff2a, ff2_b1, nullptr, bufP, CD, CD, CINNER, CD, 1.0f, 0, 0, 0);
  gemm_bf<64, 128, EPI_RES><<<dim3(4, 128, 1), blk, 0, stream>>>(
      bufP, w_ff2b, ff2_b2, bufX, bufX, CINNER, CINNER, CD, CINNER, 0.5f, 0, 0, 0);

  // ---- Output LN ----
  ln_k<0><<<dim3(CBT), blk, 0, stream>>>(bufX, out_lng, out_lnb, out);

  (void)in_sizes; (void)n_in; (void)out_size; (void)ws_size;
}